// Round 6
// baseline (443.151 us; speedup 1.0000x reference)
//
#include <hip/hip_runtime.h>

#define NN 10000
#define NE 160000
#define INV_SQRT3f 0.57735026918962576f
#define INV_SQRT2f 0.70710678118654752f

typedef short bshort8 __attribute__((ext_vector_type(8)));
typedef float floatx4 __attribute__((ext_vector_type(4)));
#define MFMA16(a,b,c) __builtin_amdgcn_mfma_f32_16x16x32_bf16((a),(b),(c),0,0,0)

__device__ __forceinline__ float sigm(float x){ return 1.f/(1.f+__expf(-x)); }
__device__ __forceinline__ float siluf(float x){ return x*sigm(x); }
__device__ __forceinline__ float sleaky(float x){ return 0.6f*x + 0.4f*x*(2.f*sigm(x)-1.f); }
// round-half-up bf16 convert: 2 VALU ops vs 5 for RNE
__device__ __forceinline__ unsigned short f2bf(float f){
  return (unsigned short)((__float_as_uint(f) + 0x8000u)>>16);
}
__device__ __forceinline__ float bf2f(unsigned short h){
  return __uint_as_float(((unsigned)h)<<16);
}
// packed 2xbf16 convert (RNE), 1 VALU op for 2 values
__device__ __forceinline__ unsigned cvtpk(float lo, float hi){
  unsigned r;
  asm("v_cvt_pk_bf16_f32 %0, %1, %2" : "=v"(r) : "v"(lo), "v"(hi));
  return r;
}
// unpack 2xbf16 from a dword: 1 VALU op each
__device__ __forceinline__ float lo16f(unsigned u){ return __uint_as_float(u<<16); }
__device__ __forceinline__ float hi16f(unsigned u){ return __uint_as_float(u & 0xffff0000u); }

// swizzled-weight segment offsets (in ushorts)
#define O_W1   0
#define O_W2   2048
#define O_WAS  30720
#define O_WAVT 67584
#define O_WAVB 75776
#define O_WVS  83968
#define O_WVVT 108544
#define O_WVVB 116736
#define O_WALP 124928
#define SWZ_TOTAL 149504

// ---------------------------------------------------------------- merged pre-pass:
//  blocks [0,625): node_pre, 16 nodes/block (fp32 GEMV -> bf16 staging;
//                  vector planes split: xy packed per-dword + z ushort plane
//                  -> e_all gathers are 64B-segment (xy) + 32B (z), zero pad)
//  blocks [625,1209): weight pre-swizzle (w_int/INV_SQRT* folded into dtp2 weights)
//  blocks [1209,3375): grid-stride zero of num/den/cnt
__global__ __launch_bounds__(256) void k_pre_all(
    const float* __restrict__ x,
    const float* __restrict__ Wsrc_s, const float* __restrict__ Wsrc_v,
    const float* __restrict__ bsrc,
    const float* __restrict__ Wdst_s, const float* __restrict__ Wdst_v,
    unsigned short* __restrict__ ms_s, unsigned short* __restrict__ md_s,
    unsigned* __restrict__ ms_vxy, unsigned* __restrict__ md_vxy,
    unsigned short* __restrict__ ms_vz, unsigned short* __restrict__ md_vz,
    const float* __restrict__ W1, const float* __restrict__ W2,
    const float* __restrict__ WAs, const float* __restrict__ WAv,
    const float* __restrict__ WVs, const float* __restrict__ WVv,
    const float* __restrict__ WAl, const float* __restrict__ w_int,
    unsigned short* __restrict__ swz,
    float* __restrict__ num, float* __restrict__ den, int* __restrict__ cnt) {
  __shared__ __align__(16) float s_s[128*16];
  __shared__ __align__(16) float s_v[192*16];
  const int tid = threadIdx.x;
  const int b = blockIdx.x;
  if (b >= 1209) {            // ---- init branch
    int base = (b-1209)*256 + tid;      // [0, 554496)
    float4 z = {0.f,0.f,0.f,0.f};
    for (int i = base; i < 800000; i += 554496) ((float4*)num)[i] = z;
    if (base < 20000) ((float4*)den)[base] = z;
    if (base < 10000) cnt[base] = 0;
    return;
  }
  if (b >= 625) {             // ---- weight swizzle branch
    int s = (b-625)*256 + tid;
    if (s >= SWZ_TOTAL) return;
    const float* src; int base, N, KT, rowOff;
    if      (s < 2048)  { base=O_W1;   src=W1;  N=64;  KT=1; rowOff=0; }
    else if (s < 30720) { base=O_W2;   src=W2;  N=448; KT=2; rowOff=0; }
    else if (s < 67584) { base=O_WAS;  src=WAs; N=192; KT=6; rowOff=0; }
    else if (s < 75776) { base=O_WAVT; src=WAv; N=64;  KT=4; rowOff=0; }
    else if (s < 83968) { base=O_WAVB; src=WAv; N=64;  KT=4; rowOff=128; }
    else if (s < 108544){ base=O_WVS;  src=WVs; N=128; KT=6; rowOff=0; }
    else if (s < 116736){ base=O_WVVT; src=WVv; N=64;  KT=4; rowOff=0; }
    else if (s < 124928){ base=O_WVVB; src=WVv; N=64;  KT=4; rowOff=128; }
    else                { base=O_WALP; src=WAl; N=128; KT=6; rowOff=0; }
    int loc = s - base;
    int j = loc & 7, l = (loc>>3)&63, kt = (loc>>9)%KT, nt = loc/(512*KT);
    int row = kt*32 + (l>>4)*8 + j + rowOff;
    int col = nt*16 + (l&15);
    // fold w_int (and the dtp2 INV_SQRT* constants) into the dtp2 weights
    float scl = 1.f;
    if      (base == O_WVS)  scl = (row < 128) ? w_int[row] : w_int[192+row]*INV_SQRT3f;
    else if (base == O_WVVT) scl = w_int[128+row];
    else if (base == O_WVVB) scl = (row < 192) ? w_int[128+row] : w_int[192+row]*INV_SQRT2f;
    swz[s] = f2bf(src[row*N + col] * scl);
    return;
  }
  // ---- node_pre branch: 16 nodes per block
  const int n0 = b*16;
  for (int idx = tid; idx < 16*320; idx += 256) {
    int n = idx/320, d = idx - n*320;
    float val = x[(n0+n)*320 + d];
    if (d < 128) s_s[d*16+n] = val;
    else         s_v[(d-128)*16+n] = val;
  }
  __syncthreads();
  {
    int g = tid>>7, j = tid&127;    // g selects nodes g*8..g*8+7
    float accs[8], accd[8];
    float bb = bsrc[j];
    #pragma unroll
    for (int i=0;i<8;i++){ accs[i]=bb; accd[i]=0.f; }
    for (int k=0;k<128;k++) {
      float w1 = Wsrc_s[k*128+j], w2 = Wdst_s[k*128+j];
      float4 a0 = *(const float4*)&s_s[k*16+g*8];
      float4 a1 = *(const float4*)&s_s[k*16+g*8+4];
      accs[0]+=a0.x*w1; accs[1]+=a0.y*w1; accs[2]+=a0.z*w1; accs[3]+=a0.w*w1;
      accs[4]+=a1.x*w1; accs[5]+=a1.y*w1; accs[6]+=a1.z*w1; accs[7]+=a1.w*w1;
      accd[0]+=a0.x*w2; accd[1]+=a0.y*w2; accd[2]+=a0.z*w2; accd[3]+=a0.w*w2;
      accd[4]+=a1.x*w2; accd[5]+=a1.y*w2; accd[6]+=a1.z*w2; accd[7]+=a1.w*w2;
    }
    #pragma unroll
    for (int i=0;i<8;i++){ int n=n0+g*8+i; ms_s[n*128+j]=f2bf(accs[i]); md_s[n*128+j]=f2bf(accd[i]); }
  }
  if (tid < 128) {
    int g = tid>>6, k = tid&63;
    if (g == 0) {   // xy components, packed dword output
      #pragma unroll
      for (int half=0; half<2; ++half) {
        float asx[8], asy[8], adx[8], ady[8];
        #pragma unroll
        for (int e=0;e<8;e++){ asx[e]=0.f; asy[e]=0.f; adx[e]=0.f; ady[e]=0.f; }
        for (int m=0;m<64;m++) {
          float w1 = Wsrc_v[m*64+k], w2 = Wdst_v[m*64+k];
          float4 x0 = *(const float4*)&s_v[(m*3+0)*16 + half*8];
          float4 x1 = *(const float4*)&s_v[(m*3+0)*16 + half*8 + 4];
          float4 y0 = *(const float4*)&s_v[(m*3+1)*16 + half*8];
          float4 y1 = *(const float4*)&s_v[(m*3+1)*16 + half*8 + 4];
          asx[0]+=x0.x*w1; asx[1]+=x0.y*w1; asx[2]+=x0.z*w1; asx[3]+=x0.w*w1;
          asx[4]+=x1.x*w1; asx[5]+=x1.y*w1; asx[6]+=x1.z*w1; asx[7]+=x1.w*w1;
          asy[0]+=y0.x*w1; asy[1]+=y0.y*w1; asy[2]+=y0.z*w1; asy[3]+=y0.w*w1;
          asy[4]+=y1.x*w1; asy[5]+=y1.y*w1; asy[6]+=y1.z*w1; asy[7]+=y1.w*w1;
          adx[0]+=x0.x*w2; adx[1]+=x0.y*w2; adx[2]+=x0.z*w2; adx[3]+=x0.w*w2;
          adx[4]+=x1.x*w2; adx[5]+=x1.y*w2; adx[6]+=x1.z*w2; adx[7]+=x1.w*w2;
          ady[0]+=y0.x*w2; ady[1]+=y0.y*w2; ady[2]+=y0.z*w2; ady[3]+=y0.w*w2;
          ady[4]+=y1.x*w2; ady[5]+=y1.y*w2; ady[6]+=y1.z*w2; ady[7]+=y1.w*w2;
        }
        #pragma unroll
        for (int e=0;e<8;e++){
          int n = n0 + half*8 + e;
          ms_vxy[n*64+k] = cvtpk(asx[e], asy[e]);
          md_vxy[n*64+k] = cvtpk(adx[e], ady[e]);
        }
      }
    } else {        // z component, ushort plane
      #pragma unroll
      for (int half=0; half<2; ++half) {
        float accs[8], accd[8];
        #pragma unroll
        for (int e=0;e<8;e++){ accs[e]=0.f; accd[e]=0.f; }
        for (int m=0;m<64;m++) {
          float w1 = Wsrc_v[m*64+k], w2 = Wdst_v[m*64+k];
          float4 v0 = *(const float4*)&s_v[(m*3+2)*16 + half*8];
          float4 v1 = *(const float4*)&s_v[(m*3+2)*16 + half*8 + 4];
          accs[0]+=v0.x*w1; accs[1]+=v0.y*w1; accs[2]+=v0.z*w1; accs[3]+=v0.w*w1;
          accs[4]+=v1.x*w1; accs[5]+=v1.y*w1; accs[6]+=v1.z*w1; accs[7]+=v1.w*w1;
          accd[0]+=v0.x*w2; accd[1]+=v0.y*w2; accd[2]+=v0.z*w2; accd[3]+=v0.w*w2;
          accd[4]+=v1.x*w2; accd[5]+=v1.y*w2; accd[6]+=v1.z*w2; accd[7]+=v1.w*w2;
        }
        #pragma unroll
        for (int e=0;e<8;e++){
          int n = n0 + half*8 + e;
          ms_vz[n*64+k] = f2bf(accs[e]);
          md_vz[n*64+k] = f2bf(accd[e]);
        }
      }
    }
  }
}

// ---------------------------------------------------------------- counting sort of edges by dst
__global__ __launch_bounds__(256) void k_hist(const int* __restrict__ edst,
                                              int* __restrict__ cnt) {
  int e = blockIdx.x*256 + threadIdx.x;
  if (e < NE) atomicAdd(&cnt[edst[e]], 1);
}

__global__ __launch_bounds__(256) void k_scan(const int* __restrict__ cnt,
                                              int* __restrict__ offs) {
  __shared__ int sc[10240];
  __shared__ int wsum[4];
  const int tid = threadIdx.x;
  const int lane = tid & 63, wave = tid >> 6;
  for (int i = tid; i < 10240; i += 256) sc[i] = (i < NN) ? cnt[i] : 0;
  __syncthreads();
  int v[40]; int s = 0;
  #pragma unroll
  for (int j=0;j<40;j++){ v[j] = sc[tid*40+j]; s += v[j]; }
  int incl = s;
  #pragma unroll
  for (int d=1; d<64; d<<=1) { int t = __shfl_up(incl, d, 64); if (lane>=d) incl += t; }
  if (lane==63) wsum[wave] = incl;
  __syncthreads();
  int wbase = 0;
  for (int w=0; w<wave; ++w) wbase += wsum[w];
  int excl = wbase + incl - s;
  #pragma unroll
  for (int j=0;j<40;j++){ int i = tid*40+j; if (i<NN) offs[i] = excl; excl += v[j]; }
}

__global__ __launch_bounds__(256) void k_scatter(const int* __restrict__ edst,
                                                 int* __restrict__ offs,
                                                 int* __restrict__ perm) {
  int e = blockIdx.x*256 + threadIdx.x;
  if (e < NE) {
    int pos = atomicAdd(&offs[edst[e]], 1);
    perm[pos] = e;
  }
}

// ---------------------------------------------------------------- fused edge pass
// vs round-5 (regressed via padded ushort4 gathers: FETCH 99->118MB):
//  * vector staging split xy-dword + z-ushort: compulsory bytes back to round-3
//    minimum (7.68MB, no pad); fused gather xy = 64B full-line segments,
//    z = 32B (mostly L2-absorbed). Theory: e_all dur ~ 0.5us/MB of FETCH+WRITE.
//  * everything else as round 5 (fused A2', 6 blk/CU, folded weights,
//    hoisted B-fragments, 16-edge scatter runs, XCD swizzle)
__global__ __launch_bounds__(256, 6) void e_all(
    const unsigned short* __restrict__ ms_s, const unsigned short* __restrict__ md_s,
    const unsigned* __restrict__ ms_vxy, const unsigned* __restrict__ md_vxy,
    const unsigned short* __restrict__ ms_vz, const unsigned short* __restrict__ md_vz,
    const int* __restrict__ esrc, const int* __restrict__ edst,
    const int* __restrict__ perm,
    const float* __restrict__ eattr, const float* __restrict__ escal,
    const float* __restrict__ rad_b1, const float* __restrict__ rad_off,
    const float* __restrict__ bact,
    const float* __restrict__ bval,
    const float* __restrict__ balpha, const float* __restrict__ alpha_dot,
    const unsigned short* __restrict__ swz,
    float* __restrict__ den, float* __restrict__ num) {
  __shared__ __align__(16) char smem[24768];
  unsigned short* ads  = (unsigned short*)smem;            // 16x200 [0,6400)
  unsigned short* at1  = (unsigned short*)(smem+6400);     // 16x136 [6400,10752)
  unsigned short* advb = (unsigned short*)(smem+10752);    // 3x16x136 [10752,23808)
  unsigned short* aes  = (unsigned short*)(smem+10752);    // alias (dead pre-A2')
  unsigned short* ah   = (unsigned short*)(smem+12032);    // alias (dead post-ha-load)
  float* vout          = (float*)(smem+10752);             // alias advb: E2 16x194, E1 16x132
  float* s_e0 = (float*)(smem+23808);
  float* s_e1 = (float*)(smem+23872);
  float* s_ex = (float*)(smem+24064);
  int* s_eid  = (int*)(smem+24576);
  int* s_src  = (int*)(smem+24640);
  int* s_dst  = (int*)(smem+24704);
  const int tid  = threadIdx.x;
  const int lane = tid & 63, wave = tid >> 6;
  const int quad = lane >> 4, l15 = lane & 15;
  // bijective XCD-chunk swizzle (10000 = 8*1250)
  const int bswz = (blockIdx.x & 7)*1250 + (blockIdx.x >> 3);
  const int eb = bswz*16;

  if (tid < 16) {
    int eid = perm[eb+tid];
    s_eid[tid] = eid; s_src[tid] = esrc[eid]; s_dst[tid] = edst[eid];
  }
  __syncthreads();
  if (tid >= 64 && tid < 128) {
    int t = tid-64, e = t>>2, q = t&3;
    float a = eattr[s_eid[e]*4+q];
    if (q == 0) s_e0[e] = a; else s_e1[(q-1)*16+e] = a;
  }
  { // packed escal staging: 256 threads x 2 values
    int e = tid>>4, i0 = (tid&15)*2;
    float2 es = *(const float2*)&escal[s_eid[e]*32+i0];
    *(unsigned*)&aes[e*40+i0] = cvtpk(es.x, es.y);
  }
  __syncthreads();

  // ---- A1: h = silu(escal@W1+b1)
  {
    int nt = wave, col = nt*16 + l15;
    bshort8 a = *(const bshort8*)&aes[l15*40 + quad*8];
    bshort8 b = *(const bshort8*)&swz[O_W1 + (nt*64 + lane)*8];
    float bb = rad_b1[col];
    floatx4 acc = {bb,bb,bb,bb};
    acc = MFMA16(a, b, acc);
    #pragma unroll
    for (int r=0;r<4;r++) ah[(quad*4+r)*72 + col] = f2bf(siluf(acc[r]));
  }
  __syncthreads();

  // ---- A2'-fused: radial tiles + dtp1 scalar AND vector parts in one stage
  {
    bshort8 ha0 = *(const bshort8*)&ah[l15*72 + quad*8];
    bshort8 ha1 = *(const bshort8*)&ah[l15*72 + 32 + quad*8];
    __syncthreads();   // ah consumed by all waves; advb-region writes follow
    int src_[4], dst_[4];
    #pragma unroll
    for (int r=0;r<4;r++){ int e=quad*4+r; src_[r]=s_src[e]; dst_[r]=s_dst[e]; }
    // w1/w2 pair tiles: one msgs gather feeds ads and at1
    #pragma unroll
    for (int p=0;p<2;p++) {
      int nt1 = wave*2+p, nt2 = nt1+8;
      int m = nt1*16 + l15;
      float o1 = rad_off[m], o2 = rad_off[128+m];
      floatx4 a1 = {o1,o1,o1,o1}, a2 = {o2,o2,o2,o2};
      a1 = MFMA16(ha0, *(const bshort8*)&swz[O_W2 + ((nt1*2+0)*64+lane)*8], a1);
      a1 = MFMA16(ha1, *(const bshort8*)&swz[O_W2 + ((nt1*2+1)*64+lane)*8], a1);
      a2 = MFMA16(ha0, *(const bshort8*)&swz[O_W2 + ((nt2*2+0)*64+lane)*8], a2);
      a2 = MFMA16(ha1, *(const bshort8*)&swz[O_W2 + ((nt2*2+1)*64+lane)*8], a2);
      #pragma unroll
      for (int r=0;r<4;r++) {
        int e = quad*4+r;
        float msgs = bf2f(ms_s[src_[r]*128+m]) + bf2f(md_s[dst_[r]*128+m]);
        ads[e*200+m] = f2bf(a1[r]*msgs*s_e0[e]);
        at1[e*136+m] = f2bf(a2[r]*msgs);
      }
    }
    // w3/w4/w5 tiles for this wave's k-slice (all three in-lane)
    floatx4 aw3, aw4, aw5;
    {
      int nt = 16 + wave; float o = rad_off[nt*16+l15];
      floatx4 acc = {o,o,o,o};
      acc = MFMA16(ha0, *(const bshort8*)&swz[O_W2 + ((nt*2+0)*64+lane)*8], acc);
      acc = MFMA16(ha1, *(const bshort8*)&swz[O_W2 + ((nt*2+1)*64+lane)*8], acc);
      aw3 = acc;
    }
    {
      int nt = 20 + wave; float o = rad_off[nt*16+l15];
      floatx4 acc = {o,o,o,o};
      acc = MFMA16(ha0, *(const bshort8*)&swz[O_W2 + ((nt*2+0)*64+lane)*8], acc);
      acc = MFMA16(ha1, *(const bshort8*)&swz[O_W2 + ((nt*2+1)*64+lane)*8], acc);
      aw4 = acc;
    }
    {
      int nt = 24 + wave; float o = rad_off[nt*16+l15];
      floatx4 acc = {o,o,o,o};
      acc = MFMA16(ha0, *(const bshort8*)&swz[O_W2 + ((nt*2+0)*64+lane)*8], acc);
      acc = MFMA16(ha1, *(const bshort8*)&swz[O_W2 + ((nt*2+1)*64+lane)*8], acc);
      aw5 = acc;
    }
    // fused dtp1 vector part at k = wave*16+l15; xy 64B-segment + z 32B gathers
    const int k = wave*16 + l15;
    #pragma unroll
    for (int r=0;r<4;r++) {
      int e = quad*4 + r;
      unsigned sxy = ms_vxy[src_[r]*64 + k];
      unsigned dxy = md_vxy[dst_[r]*64 + k];
      float vz = bf2f(ms_vz[src_[r]*64 + k]) + bf2f(md_vz[dst_[r]*64 + k]);
      float vx = lo16f(sxy) + lo16f(dxy);
      float vy = hi16f(sxy) + hi16f(dxy);
      float ex1 = s_e1[0+e], ey1 = s_e1[16+e], ez1 = s_e1[32+e];
      float e0 = s_e0[e];
      float d = vx*ex1 + vy*ey1 + vz*ez1;
      ads[e*200+128+k] = f2bf(aw4[r]*d*INV_SQRT3f);
      float w3v = aw3[r]*e0;
      float w5  = aw5[r]*INV_SQRT2f;
      advb[0*2176 + e*136 + k] = f2bf(w3v*vx);
      advb[1*2176 + e*136 + k] = f2bf(w3v*vy);
      advb[2*2176 + e*136 + k] = f2bf(w3v*vz);
      advb[0*2176 + e*136 + 64+k] = f2bf(w5*(vy*ez1 - vz*ey1));
      advb[1*2176 + e*136 + 64+k] = f2bf(w5*(vz*ex1 - vx*ez1));
      advb[2*2176 + e*136 + 64+k] = f2bf(w5*(vx*ey1 - vy*ex1));
    }
  }
  __syncthreads();

  // ---- CD (fused): all MFMAs with fragments in regs, then activations + dtp2 writes
  floatx4 sc0, sc1, sc2, gsa, gb0, gb1, gb2;
  {
    bshort8 fa[6];
    #pragma unroll
    for (int kt=0;kt<6;kt++) fa[kt] = *(const bshort8*)&ads[l15*200 + kt*32 + quad*8];
    // alpha logits + ex/den (run-compressed den atomics over 4 sorted edges)
    #pragma unroll
    for (int t=0;t<2;t++) {
      int h = wave*2 + t;
      int col = h*16 + l15;
      float bb = balpha[col];
      floatx4 acc = {bb,bb,bb,bb};
      #pragma unroll
      for (int kt=0;kt<6;kt++)
        acc = MFMA16(fa[kt], *(const bshort8*)&swz[O_WALP + ((h*6+kt)*64+lane)*8], acc);
      float ad = alpha_dot[col];
      float exv[4];
      #pragma unroll
      for (int r=0;r<4;r++) {
        float p = sleaky(acc[r])*ad;
        p += __shfl_xor(p, 1);
        p += __shfl_xor(p, 2);
        p += __shfl_xor(p, 4);
        p += __shfl_xor(p, 8);
        float ex = __expf(p);
        exv[r] = ex;
        if (l15 == 0) s_ex[(quad*4+r)*8+h] = ex;
      }
      if (l15 == 0) {
        float racc = exv[0]; int cur = s_dst[quad*4];
        #pragma unroll
        for (int r=1;r<4;r++) {
          int d = s_dst[quad*4+r];
          if (d != cur) { atomicAdd(&den[cur*8+h], racc); racc = 0.f; cur = d; }
          racc += exv[r];
        }
        atomicAdd(&den[cur*8+h], racc);
      }
    }
    // scal tiles
    {
      float bb = bact[wave*16 + l15];
      floatx4 a0 = {bb,bb,bb,bb};
      #pragma unroll
      for (int kt=0;kt<6;kt++)
        a0 = MFMA16(fa[kt], *(const bshort8*)&swz[O_WAS + ((wave*6+kt)*64+lane)*8], a0);
      sc0 = a0;
    }
    {
      float bb = bact[(wave+4)*16 + l15];
      floatx4 a1 = {bb,bb,bb,bb};
      #pragma unroll
      for (int kt=0;kt<6;kt++)
        a1 = MFMA16(fa[kt], *(const bshort8*)&swz[O_WAS + (((wave+4)*6+kt)*64+lane)*8], a1);
      sc1 = a1;
    }
    {
      float bb = bact[(wave+8)*16 + l15];
      floatx4 a2 = {bb,bb,bb,bb};
      #pragma unroll
      for (int kt=0;kt<6;kt++)
        a2 = MFMA16(fa[kt], *(const bshort8*)&swz[O_WAS + (((wave+8)*6+kt)*64+lane)*8], a2);
      sc2 = a2;
    }
    bshort8 ft[4];
    #pragma unroll
    for (int kt=0;kt<4;kt++) ft[kt] = *(const bshort8*)&at1[l15*136 + kt*32 + quad*8];
    {
      floatx4 acc = {0.f,0.f,0.f,0.f};
      #pragma unroll
      for (int kt=0;kt<4;kt++)
        acc = MFMA16(ft[kt], *(const bshort8*)&swz[O_WAVT + ((wave*4+kt)*64+lane)*8], acc);
      gsa = acc;
    }
    { // hoist c-invariant WAVB fragments (used 3x)
      bshort8 wb[4];
      #pragma unroll
      for (int kt=0;kt<4;kt++) wb[kt] = *(const bshort8*)&swz[O_WAVB + ((wave*4+kt)*64+lane)*8];
      #pragma unroll
      for (int c=0;c<3;c++) {
        floatx4 acc = {0.f,0.f,0.f,0.f};
        #pragma unroll
        for (int kt=0;kt<4;kt++) {
          bshort8 fb = *(const bshort8*)&advb[c*2176 + l15*136 + kt*32 + quad*8];
          acc = MFMA16(fb, wb[kt], acc);
        }
        if (c==0) gb0 = acc; else if (c==1) gb1 = acc; else gb2 = acc;
      }
    }
  }
  __syncthreads();   // all fragment reads done; safe to overwrite ads/at1/advb

  // ---- CDw: activations + dtp2 writes (w_int pre-folded into dtp2 weights)
  {
    const int k = wave*16 + l15;       // 0..63
    #pragma unroll
    for (int r=0;r<4;r++) {
      int row = quad*4 + r;
      float e0 = s_e0[row];
      { // silu path, tile t0: m = k
        float v = siluf(sc0[r]);
        ads[row*200+k] = f2bf(v*e0);
        at1[row*136+k] = f2bf(v);
      }
      { // silu path, tile t1: m = 64+k
        float v = siluf(sc1[r]);
        ads[row*200+64+k] = f2bf(v*e0);
        at1[row*136+64+k] = f2bf(v);
      }
      { // gated vector path (tile t2 gives scal[128+k])
        float sg = sigm(sc2[r]);
        float gs = gsa[r];
        float ex1 = s_e1[0+row], ey1 = s_e1[16+row], ez1 = s_e1[32+row];
        float v0 = (gs*ex1 + gb0[r])*sg;
        float v1 = (gs*ey1 + gb1[r])*sg;
        float v2 = (gs*ez1 + gb2[r])*sg;
        float d = v0*ex1 + v1*ey1 + v2*ez1;
        ads[row*200+128+k] = f2bf(d);
        advb[0*2176 + row*136 + k] = f2bf(v0*e0);
        advb[1*2176 + row*136 + k] = f2bf(v1*e0);
        advb[2*2176 + row*136 + k] = f2bf(v2*e0);
        advb[0*2176 + row*136 + 64+k] = f2bf(v1*ez1 - v2*ey1);
        advb[1*2176 + row*136 + 64+k] = f2bf(v2*ex1 - v0*ez1);
        advb[2*2176 + row*136 + 64+k] = f2bf(v0*ey1 - v1*ex1);
      }
    }
  }
  __syncthreads();

  // ---- E2: vector MFMAs (ft from at1, fb from advb) -> vout (aliases advb)
  {
    bshort8 ft[4];
    #pragma unroll
    for (int kt=0;kt<4;kt++) ft[kt] = *(const bshort8*)&at1[l15*136 + kt*32 + quad*8];
    floatx4 vsh = {0.f,0.f,0.f,0.f};
    #pragma unroll
    for (int kt=0;kt<4;kt++)
      vsh = MFMA16(ft[kt], *(const bshort8*)&swz[O_WVVT + ((wave*4+kt)*64+lane)*8], vsh);
    floatx4 vb0, vb1, vb2;
    { // hoist c-invariant WVVB fragments (used 3x)
      bshort8 wb[4];
      #pragma unroll
      for (int kt=0;kt<4;kt++) wb[kt] = *(const bshort8*)&swz[O_WVVB + ((wave*4+kt)*64+lane)*8];
      #pragma unroll
      for (int c=0;c<3;c++) {
        floatx4 acc = {0.f,0.f,0.f,0.f};
        #pragma unroll
        for (int kt=0;kt<4;kt++) {
          bshort8 fb = *(const bshort8*)&advb[c*2176 + l15*136 + kt*32 + quad*8];
          acc = MFMA16(fb, wb[kt], acc);
        }
        if (c==0) vb0 = acc; else if (c==1) vb1 = acc; else vb2 = acc;
      }
    }
    __syncthreads();   // all fb reads done -> safe to overwrite advb with vout
    const int k = wave*16 + l15;
    const int h = k>>3, q = k&7;
    #pragma unroll
    for (int r=0;r<4;r++) {
      int row = quad*4 + r;
      float exr = s_ex[row*8+h];
      vout[row*194 + h*24 + q*3 + 0] = (vb0[r] + s_e1[0*16+row]*vsh[r])*exr;
      vout[row*194 + h*24 + q*3 + 1] = (vb1[r] + s_e1[1*16+row]*vsh[r])*exr;
      vout[row*194 + h*24 + q*3 + 2] = (vb2[r] + s_e1[2*16+row]*vsh[r])*exr;
    }
  }
  __syncthreads();

  // ---- F2: 16-edge run-compressed vector scatter
  if (tid < 192) {
    const int jj = tid;
    const int h = jj/24, rr = jj - h*24;
    float acc = 0.f; int cur = s_dst[0];
    #pragma unroll
    for (int e = 0; e < 16; ++e) {
      int d = s_dst[e];
      if (d != cur) { atomicAdd(&num[cur*320 + h*40 + 16 + rr], acc); acc = 0.f; cur = d; }
      acc += vout[e*194 + jj];
    }
    atomicAdd(&num[cur*320 + h*40 + 16 + rr], acc);
  }
  __syncthreads();

  // ---- E1: scalar-out MFMAs (fa from ads, untouched) -> vout (advb region)
  {
    bshort8 fa[6];
    #pragma unroll
    for (int kt=0;kt<6;kt++) fa[kt] = *(const bshort8*)&ads[l15*200 + kt*32 + quad*8];
    #pragma unroll
    for (int t=0;t<2;t++) {
      int h = wave + 4*t;
      float bb = bval[h*16 + l15];
      floatx4 acc = {bb,bb,bb,bb};
      #pragma unroll
      for (int kt=0;kt<6;kt++)
        acc = MFMA16(fa[kt], *(const bshort8*)&swz[O_WVS + ((h*6+kt)*64+lane)*8], acc);
      #pragma unroll
      for (int r=0;r<4;r++) {
        int row = quad*4 + r;
        vout[row*132 + h*16 + l15] = acc[r]*s_ex[row*8+h];
      }
    }
  }
  __syncthreads();

  // ---- F1: 16-edge run-compressed scalar scatter
  if (tid < 128) {
    const int j = tid, h = j>>4, jj = j&15;
    float acc = 0.f; int cur = s_dst[0];
    #pragma unroll
    for (int e = 0; e < 16; ++e) {
      int d = s_dst[e];
      if (d != cur) { atomicAdd(&num[cur*320 + h*40 + jj], acc); acc = 0.f; cur = d; }
      acc += vout[e*132 + j];
    }
    atomicAdd(&num[cur*320 + h*40 + jj], acc);
  }
}

// ---------------------------------------------------------------- node post (fp32 GEMV, 16 nodes/block)
__global__ __launch_bounds__(256) void node_post(
    const float* __restrict__ num, const float* __restrict__ den,
    const float* __restrict__ Wproj_s, const float* __restrict__ bproj,
    const float* __restrict__ Wproj_v, float* __restrict__ out) {
  __shared__ __align__(16) float s_ns[128*16];
  __shared__ __align__(16) float s_nv[192*16];
  const int tid = threadIdx.x;
  const int n0 = blockIdx.x*16;
  for (int idx = tid; idx < 16*320; idx += 256) {
    int n = idx/320, j = idx - n*320;
    int h = j/40, r = j - h*40;
    float a = num[(n0+n)*320+j] / (den[(n0+n)*8+h] + 1e-16f);
    if (r < 16) s_ns[(h*16+r)*16+n] = a;
    else        s_nv[(h*24 + (r-16))*16+n] = a;
  }
  __syncthreads();
  {
    int g = tid>>7, j = tid&127;
    float acc[8]; float b = bproj[j];
    #pragma unroll
    for (int i=0;i<8;i++) acc[i]=b;
    for (int k=0;k<128;k++) {
      float wv = Wproj_s[k*128+j];
      float4 a0 = *(const float4*)&s_ns[k*16+g*8];
      float4 a1 = *(const float4*)&s_ns[k*16+g*8+4];
      acc[0]+=a0.x*wv; acc[1]+=a0.y*wv; acc[2]+=a0.z*wv; acc[3]+=a0.w*wv;
      acc[4]+=a1.x*wv; acc[5]+=a1.y*wv; acc[6]+=a1.z*wv; acc[7]+=a1.w*wv;
    }
    #pragma unroll
    for (int i=0;i<8;i++) out[(n0+g*8+i)*320 + j] = acc[i];
  }
  if (tid < 192) {
    int c = tid>>6, k = tid&63;
    #pragma unroll
    for (int half=0; half<2; ++half) {
      float acc[8];
      #pragma unroll
      for (int e=0;e<8;e++) acc[e]=0.f;
      for (int m=0;m<64;m++) {
        float wv = Wproj_v[m*64+k];
        float4 v0 = *(const float4*)&s_nv[(m*3+c)*16 + half*8];
        float4 v1 = *(const float4*)&s_nv[(m*3+c)*16 + half*8 + 4];
        acc[0]+=v0.x*wv; acc[1]+=v0.y*wv; acc[2]+=v0.z*wv; acc[3]+=v0.w*wv;
        acc[4]+=v1.x*wv; acc[5]+=v1.y*wv; acc[6]+=v1.z*wv; acc[7]+=v1.w*wv;
      }
      #pragma unroll
      for (int e=0;e<8;e++) out[(n0+half*8+e)*320 + 128 + k*3 + c] = acc[e];
    }
  }
}

// ---------------------------------------------------------------- launch
extern "C" void kernel_launch(void* const* d_in, const int* in_sizes, int n_in,
                              void* d_out, int out_size, void* d_ws, size_t ws_size,
                              hipStream_t stream) {
  (void)in_sizes; (void)n_in; (void)out_size; (void)ws_size;
  const float* node_input = (const float*)d_in[0];
  const int*   esrc       = (const int*)d_in[1];
  const int*   edst       = (const int*)d_in[2];
  const float* eattr      = (const float*)d_in[3];
  const float* escal      = (const float*)d_in[4];
  const float* Wsrc_s     = (const float*)d_in[5];
  const float* Wsrc_v     = (const float*)d_in[6];
  const float* bsrc       = (const float*)d_in[7];
  const float* Wdst_s     = (const float*)d_in[8];
  const float* Wdst_v     = (const float*)d_in[9];
  const float* rad_W1     = (const float*)d_in[10];
  const float* rad_b1     = (const float*)d_in[11];
  const float* rad_W2     = (const float*)d_in[12];
  const float* rad_off    = (const float*)d_in[13];
  const float* Wact_s     = (const float*)d_in[14];
  const float* bact       = (const float*)d_in[15];
  const float* Wact_v     = (const float*)d_in[16];
  const float* Walpha     = (const float*)d_in[17];
  const float* balpha     = (const float*)d_in[18];
  const float* w_int      = (const float*)d_in[19];
  const float* Wval_s     = (const float*)d_in[20];
  const float* bval       = (const float*)d_in[21];
  const float* Wval_v     = (const float*)d_in[22];
  const float* alpha_dot  = (const float*)d_in[23];
  const float* Wproj_s    = (const float*)d_in[24];
  const float* bproj      = (const float*)d_in[25];
  const float* Wproj_v    = (const float*)d_in[26];
  float* out = (float*)d_out;

  char* wsb = (char*)d_ws;
  unsigned short* ms_s16 = (unsigned short*)(wsb);               //  2,560,000 B
  unsigned short* md_s16 = (unsigned short*)(wsb + 2560000);     //  2,560,000 B
  unsigned* ms_vxy       = (unsigned*)(wsb + 5120000);           //  2,560,000 B
  unsigned* md_vxy       = (unsigned*)(wsb + 7680000);           //  2,560,000 B
  unsigned short* ms_vz  = (unsigned short*)(wsb + 10240000);    //  1,280,000 B
  unsigned short* md_vz  = (unsigned short*)(wsb + 11520000);    //  1,280,000 B
  float* den             = (float*)(wsb + 12800000);             //    320,000 B
  float* num             = (float*)(wsb + 13120000);             // 12,800,000 B
  unsigned short* swz    = (unsigned short*)(wsb + 25920000);    //    299,008 B
  int* cnt  = (int*)(wsb + 26220032);                            //     40,000 B
  int* offs = (int*)(wsb + 26260032);                            //     40,000 B
  int* perm = (int*)(wsb + 26300032);                            //    640,000 B -> ~26.9 MB

  k_pre_all<<<3375, 256, 0, stream>>>(node_input, Wsrc_s, Wsrc_v, bsrc, Wdst_s, Wdst_v,
                                      ms_s16, md_s16, ms_vxy, md_vxy, ms_vz, md_vz,
                                      rad_W1, rad_W2, Wact_s, Wact_v, Wval_s, Wval_v,
                                      Walpha, w_int, swz, num, den, cnt);
  k_hist<<<625, 256, 0, stream>>>(edst, cnt);
  k_scan<<<1, 256, 0, stream>>>(cnt, offs);
  k_scatter<<<625, 256, 0, stream>>>(edst, offs, perm);
  e_all<<<10000, 256, 0, stream>>>(ms_s16, md_s16, ms_vxy, md_vxy, ms_vz, md_vz,
                                   esrc, edst, perm, eattr, escal,
                                   rad_b1, rad_off, bact, bval,
                                   balpha, alpha_dot, swz, den, num);
  node_post<<<625, 256, 0, stream>>>(num, den, Wproj_s, bproj, Wproj_v, out);
}

// Round 7
// 382.270 us; speedup vs baseline: 1.1593x; 1.1593x over previous
//
#include <hip/hip_runtime.h>

#define NN 10000
#define NE 160000
#define INV_SQRT3f 0.57735026918962576f
#define INV_SQRT2f 0.70710678118654752f
#define VPLU 640000   // vector plane length (NN*64 ushorts)

typedef short bshort8 __attribute__((ext_vector_type(8)));
typedef float floatx4 __attribute__((ext_vector_type(4)));
#define MFMA16(a,b,c) __builtin_amdgcn_mfma_f32_16x16x32_bf16((a),(b),(c),0,0,0)

__device__ __forceinline__ float sigm(float x){ return 1.f/(1.f+__expf(-x)); }
__device__ __forceinline__ float siluf(float x){ return x*sigm(x); }
__device__ __forceinline__ float sleaky(float x){ return 0.6f*x + 0.4f*x*(2.f*sigm(x)-1.f); }
// round-half-up bf16 convert: 2 VALU ops vs 5 for RNE
__device__ __forceinline__ unsigned short f2bf(float f){
  return (unsigned short)((__float_as_uint(f) + 0x8000u)>>16);
}
__device__ __forceinline__ float bf2f(unsigned short h){
  return __uint_as_float(((unsigned)h)<<16);
}
// packed 2xbf16 convert (RNE), 1 VALU op for 2 values
__device__ __forceinline__ unsigned cvtpk(float lo, float hi){
  unsigned r;
  asm("v_cvt_pk_bf16_f32 %0, %1, %2" : "=v"(r) : "v"(lo), "v"(hi));
  return r;
}
// unpack 2xbf16 from a dword: 1 VALU op each
__device__ __forceinline__ float lo16f(unsigned u){ return __uint_as_float(u<<16); }
__device__ __forceinline__ float hi16f(unsigned u){ return __uint_as_float(u & 0xffff0000u); }

// swizzled-weight segment offsets (in ushorts)
#define O_W1   0
#define O_W2   2048
#define O_WAS  30720
#define O_WAVT 67584
#define O_WAVB 75776
#define O_WVS  83968
#define O_WVVT 108544
#define O_WVVB 116736
#define O_WALP 124928
#define SWZ_TOTAL 149504

// ---------------------------------------------------------------- merged pre-pass:
//  blocks [0,625): node_pre, 16 nodes/block (fp32 GEMV -> bf16 planar staging)
//  blocks [625,1209): weight pre-swizzle (w_int/INV_SQRT* folded into dtp2 weights)
//  blocks [1209,3375): grid-stride zero of num/den/cnt
__global__ __launch_bounds__(256) void k_pre_all(
    const float* __restrict__ x,
    const float* __restrict__ Wsrc_s, const float* __restrict__ Wsrc_v,
    const float* __restrict__ bsrc,
    const float* __restrict__ Wdst_s, const float* __restrict__ Wdst_v,
    unsigned short* __restrict__ ms_s, unsigned short* __restrict__ md_s,
    unsigned short* __restrict__ ms_v, unsigned short* __restrict__ md_v,
    const float* __restrict__ W1, const float* __restrict__ W2,
    const float* __restrict__ WAs, const float* __restrict__ WAv,
    const float* __restrict__ WVs, const float* __restrict__ WVv,
    const float* __restrict__ WAl, const float* __restrict__ w_int,
    unsigned short* __restrict__ swz,
    float* __restrict__ num, float* __restrict__ den, int* __restrict__ cnt) {
  __shared__ __align__(16) float s_s[128*16];
  __shared__ __align__(16) float s_v[192*16];
  const int tid = threadIdx.x;
  const int b = blockIdx.x;
  if (b >= 1209) {            // ---- init branch
    int base = (b-1209)*256 + tid;      // [0, 554496)
    float4 z = {0.f,0.f,0.f,0.f};
    for (int i = base; i < 800000; i += 554496) ((float4*)num)[i] = z;
    if (base < 20000) ((float4*)den)[base] = z;
    if (base < 10000) cnt[base] = 0;
    return;
  }
  if (b >= 625) {             // ---- weight swizzle branch
    int s = (b-625)*256 + tid;
    if (s >= SWZ_TOTAL) return;
    const float* src; int base, N, KT, rowOff;
    if      (s < 2048)  { base=O_W1;   src=W1;  N=64;  KT=1; rowOff=0; }
    else if (s < 30720) { base=O_W2;   src=W2;  N=448; KT=2; rowOff=0; }
    else if (s < 67584) { base=O_WAS;  src=WAs; N=192; KT=6; rowOff=0; }
    else if (s < 75776) { base=O_WAVT; src=WAv; N=64;  KT=4; rowOff=0; }
    else if (s < 83968) { base=O_WAVB; src=WAv; N=64;  KT=4; rowOff=128; }
    else if (s < 108544){ base=O_WVS;  src=WVs; N=128; KT=6; rowOff=0; }
    else if (s < 116736){ base=O_WVVT; src=WVv; N=64;  KT=4; rowOff=0; }
    else if (s < 124928){ base=O_WVVB; src=WVv; N=64;  KT=4; rowOff=128; }
    else                { base=O_WALP; src=WAl; N=128; KT=6; rowOff=0; }
    int loc = s - base;
    int j = loc & 7, l = (loc>>3)&63, kt = (loc>>9)%KT, nt = loc/(512*KT);
    int row = kt*32 + (l>>4)*8 + j + rowOff;
    int col = nt*16 + (l&15);
    // fold w_int (and the dtp2 INV_SQRT* constants) into the dtp2 weights
    float scl = 1.f;
    if      (base == O_WVS)  scl = (row < 128) ? w_int[row] : w_int[192+row]*INV_SQRT3f;
    else if (base == O_WVVT) scl = w_int[128+row];
    else if (base == O_WVVB) scl = (row < 192) ? w_int[128+row] : w_int[192+row]*INV_SQRT2f;
    swz[s] = f2bf(src[row*N + col] * scl);
    return;
  }
  // ---- node_pre branch: 16 nodes per block, planar vector staging
  const int n0 = b*16;
  for (int idx = tid; idx < 16*320; idx += 256) {
    int n = idx/320, d = idx - n*320;
    float val = x[(n0+n)*320 + d];
    if (d < 128) s_s[d*16+n] = val;
    else         s_v[(d-128)*16+n] = val;
  }
  __syncthreads();
  {
    int g = tid>>7, j = tid&127;    // g selects nodes g*8..g*8+7
    float accs[8], accd[8];
    float bb = bsrc[j];
    #pragma unroll
    for (int i=0;i<8;i++){ accs[i]=bb; accd[i]=0.f; }
    for (int k=0;k<128;k++) {
      float w1 = Wsrc_s[k*128+j], w2 = Wdst_s[k*128+j];
      float4 a0 = *(const float4*)&s_s[k*16+g*8];
      float4 a1 = *(const float4*)&s_s[k*16+g*8+4];
      accs[0]+=a0.x*w1; accs[1]+=a0.y*w1; accs[2]+=a0.z*w1; accs[3]+=a0.w*w1;
      accs[4]+=a1.x*w1; accs[5]+=a1.y*w1; accs[6]+=a1.z*w1; accs[7]+=a1.w*w1;
      accd[0]+=a0.x*w2; accd[1]+=a0.y*w2; accd[2]+=a0.z*w2; accd[3]+=a0.w*w2;
      accd[4]+=a1.x*w2; accd[5]+=a1.y*w2; accd[6]+=a1.z*w2; accd[7]+=a1.w*w2;
    }
    #pragma unroll
    for (int i=0;i<8;i++){ int n=n0+g*8+i; ms_s[n*128+j]=f2bf(accs[i]); md_s[n*128+j]=f2bf(accd[i]); }
  }
  if (tid < 192) {
    int c = tid>>6, k = tid&63;
    #pragma unroll
    for (int half=0; half<2; ++half) {
      float accs[8], accd[8];
      #pragma unroll
      for (int e=0;e<8;e++){ accs[e]=0.f; accd[e]=0.f; }
      for (int m=0;m<64;m++) {
        float w1 = Wsrc_v[m*64+k], w2 = Wdst_v[m*64+k];
        float4 v0 = *(const float4*)&s_v[(m*3+c)*16 + half*8];
        float4 v1 = *(const float4*)&s_v[(m*3+c)*16 + half*8 + 4];
        accs[0]+=v0.x*w1; accs[1]+=v0.y*w1; accs[2]+=v0.z*w1; accs[3]+=v0.w*w1;
        accs[4]+=v1.x*w1; accs[5]+=v1.y*w1; accs[6]+=v1.z*w1; accs[7]+=v1.w*w1;
        accd[0]+=v0.x*w2; accd[1]+=v0.y*w2; accd[2]+=v0.z*w2; accd[3]+=v0.w*w2;
        accd[4]+=v1.x*w2; accd[5]+=v1.y*w2; accd[6]+=v1.z*w2; accd[7]+=v1.w*w2;
      }
      #pragma unroll
      for (int e=0;e<8;e++){
        int n = n0 + half*8 + e;
        ms_v[c*VPLU + n*64 + k] = f2bf(accs[e]);
        md_v[c*VPLU + n*64 + k] = f2bf(accd[e]);
      }
    }
  }
}

// ---------------------------------------------------------------- counting sort of edges by dst
__global__ __launch_bounds__(256) void k_hist(const int* __restrict__ edst,
                                              int* __restrict__ cnt) {
  int e = blockIdx.x*256 + threadIdx.x;
  if (e < NE) atomicAdd(&cnt[edst[e]], 1);
}

__global__ __launch_bounds__(256) void k_scan(const int* __restrict__ cnt,
                                              int* __restrict__ offs) {
  __shared__ int sc[10240];
  __shared__ int wsum[4];
  const int tid = threadIdx.x;
  const int lane = tid & 63, wave = tid >> 6;
  for (int i = tid; i < 10240; i += 256) sc[i] = (i < NN) ? cnt[i] : 0;
  __syncthreads();
  int v[40]; int s = 0;
  #pragma unroll
  for (int j=0;j<40;j++){ v[j] = sc[tid*40+j]; s += v[j]; }
  int incl = s;
  #pragma unroll
  for (int d=1; d<64; d<<=1) { int t = __shfl_up(incl, d, 64); if (lane>=d) incl += t; }
  if (lane==63) wsum[wave] = incl;
  __syncthreads();
  int wbase = 0;
  for (int w=0; w<wave; ++w) wbase += wsum[w];
  int excl = wbase + incl - s;
  #pragma unroll
  for (int j=0;j<40;j++){ int i = tid*40+j; if (i<NN) offs[i] = excl; excl += v[j]; }
}

__global__ __launch_bounds__(256) void k_scatter(const int* __restrict__ edst,
                                                 int* __restrict__ offs,
                                                 int* __restrict__ perm) {
  int e = blockIdx.x*256 + threadIdx.x;
  if (e < NE) {
    int pos = atomicAdd(&offs[edst[e]], 1);
    perm[pos] = e;
  }
}

// ---------------------------------------------------------------- fused edge pass
// REVERT of rounds 4-6's fused A2' vector gather (which inflated FETCH 74->99-118MB
// and WRITE 62->116-126MB: each edge's vector row read by 16 lanes of 4 different
// waves = 4x L2 requests + eviction pressure). Back to round-3's dedicated
// B-vector stage: 32 lanes/edge, dword-pair loads, 128B contiguous segments,
// each row read once per plane. Kept from rounds 4-6 (independently validated):
//  * w_int folded into dtp2 weights (CDw sheds loads/muls)
//  * WAVB/WVVB fragments hoisted (3x reuse)
//  * merged pre-pass, 16-node pre/post, LDS-staged k_scan, XCD swizzle
// LDS 30912 B -> 5 blocks/CU (the r3-proven config).
__global__ __launch_bounds__(256, 5) void e_all(
    const unsigned short* __restrict__ ms_s, const unsigned short* __restrict__ md_s,
    const unsigned short* __restrict__ ms_v, const unsigned short* __restrict__ md_v,
    const int* __restrict__ esrc, const int* __restrict__ edst,
    const int* __restrict__ perm,
    const float* __restrict__ eattr, const float* __restrict__ escal,
    const float* __restrict__ rad_b1, const float* __restrict__ rad_off,
    const float* __restrict__ bact,
    const float* __restrict__ bval,
    const float* __restrict__ balpha, const float* __restrict__ alpha_dot,
    const unsigned short* __restrict__ swz,
    float* __restrict__ den, float* __restrict__ num) {
  __shared__ __align__(16) char smem[30912];
  unsigned short* sw_v = (unsigned short*)smem;            // 16x192 (w3|w4|w5) [0,6144)
  float* vout          = (float*)smem;                     // E1: 16x132, E2: 16x194 f32 [0,12544)
  unsigned short* ads  = (unsigned short*)(smem+6144);     // 16x200 (ds / vs) [6144,12544)
  unsigned short* at1  = (unsigned short*)(smem+12544);    // 16x136 (t1 / t2)
  unsigned short* advb = (unsigned short*)(smem+16896);    // 3x16x136 (dvB / vvB)
  unsigned short* aes  = (unsigned short*)(smem+16896);    // alias (dead pre-B)
  unsigned short* ah   = (unsigned short*)(smem+19456);    // alias (dead pre-B)
  float* s_e0 = (float*)(smem+29952);
  float* s_e1 = (float*)(smem+30016);
  float* s_ex = (float*)(smem+30208);
  int* s_eid  = (int*)(smem+30720);
  int* s_src  = (int*)(smem+30784);
  int* s_dst  = (int*)(smem+30848);
  const int tid  = threadIdx.x;
  const int lane = tid & 63, wave = tid >> 6;
  const int quad = lane >> 4, l15 = lane & 15;
  // bijective XCD-chunk swizzle (10000 = 8*1250)
  const int bswz = (blockIdx.x & 7)*1250 + (blockIdx.x >> 3);
  const int eb = bswz*16;

  if (tid < 16) {
    int eid = perm[eb+tid];
    s_eid[tid] = eid; s_src[tid] = esrc[eid]; s_dst[tid] = edst[eid];
  }
  __syncthreads();
  if (tid >= 64 && tid < 128) {
    int t = tid-64, e = t>>2, q = t&3;
    float a = eattr[s_eid[e]*4+q];
    if (q == 0) s_e0[e] = a; else s_e1[(q-1)*16+e] = a;
  }
  { // packed escal staging: 256 threads x 2 values
    int e = tid>>4, i0 = (tid&15)*2;
    float2 es = *(const float2*)&escal[s_eid[e]*32+i0];
    *(unsigned*)&aes[e*40+i0] = cvtpk(es.x, es.y);
  }
  __syncthreads();

  // ---- A1: h = silu(escal@W1+b1)
  {
    int nt = wave, col = nt*16 + l15;
    bshort8 a = *(const bshort8*)&aes[l15*40 + quad*8];
    bshort8 b = *(const bshort8*)&swz[O_W1 + (nt*64 + lane)*8];
    float bb = rad_b1[col];
    floatx4 acc = {bb,bb,bb,bb};
    acc = MFMA16(a, b, acc);
    #pragma unroll
    for (int r=0;r<4;r++) ah[(quad*4+r)*72 + col] = f2bf(siluf(acc[r]));
  }
  __syncthreads();

  // ---- A2': w tiles + fused B-scalar.
  //   w1/w2 (cols 0..255): lane holds w1[e][m] and w2[e][m] for the SAME (e,m)
  //   by pairing tiles nt and nt+8 -> one msgs gather feeds ads and at1.
  //   w3/w4/w5 (cols 256..447): store bf16 w to sw_v for the B-vector stage.
  {
    bshort8 ha0 = *(const bshort8*)&ah[l15*72 + quad*8];
    bshort8 ha1 = *(const bshort8*)&ah[l15*72 + 32 + quad*8];
    int src_[4], dst_[4];
    #pragma unroll
    for (int r=0;r<4;r++){ int e=quad*4+r; src_[r]=s_src[e]; dst_[r]=s_dst[e]; }
    #pragma unroll
    for (int p=0;p<2;p++) {
      int nt1 = wave*2+p, nt2 = nt1+8;
      int m = nt1*16 + l15;
      float o1 = rad_off[m], o2 = rad_off[128+m];
      floatx4 a1 = {o1,o1,o1,o1}, a2 = {o2,o2,o2,o2};
      a1 = MFMA16(ha0, *(const bshort8*)&swz[O_W2 + ((nt1*2+0)*64+lane)*8], a1);
      a1 = MFMA16(ha1, *(const bshort8*)&swz[O_W2 + ((nt1*2+1)*64+lane)*8], a1);
      a2 = MFMA16(ha0, *(const bshort8*)&swz[O_W2 + ((nt2*2+0)*64+lane)*8], a2);
      a2 = MFMA16(ha1, *(const bshort8*)&swz[O_W2 + ((nt2*2+1)*64+lane)*8], a2);
      #pragma unroll
      for (int r=0;r<4;r++) {
        int e = quad*4+r;
        float msgs = bf2f(ms_s[src_[r]*128+m]) + bf2f(md_s[dst_[r]*128+m]);
        ads[e*200+m] = f2bf(a1[r]*msgs*s_e0[e]);
        at1[e*136+m] = f2bf(a2[r]*msgs);
      }
    }
    #pragma unroll
    for (int q=0;q<3;q++) {
      int nt = 16 + wave*3 + q, col = nt*16 + l15;
      float o = rad_off[col];
      floatx4 acc = {o,o,o,o};
      acc = MFMA16(ha0, *(const bshort8*)&swz[O_W2 + ((nt*2+0)*64+lane)*8], acc);
      acc = MFMA16(ha1, *(const bshort8*)&swz[O_W2 + ((nt*2+1)*64+lane)*8], acc);
      #pragma unroll
      for (int r=0;r<4;r++) sw_v[(quad*4+r)*192 + (col-256)] = f2bf(acc[r]);
    }
  }
  __syncthreads();

  // ---- B-vector: dtp1 vector part, k-pairs (packed bf16x2 loads + cvt_pk writes)
  //      32 lanes/edge, 128B contiguous segments per plane, each row read once.
  #pragma unroll
  for (int it = 0; it < 2; ++it) {
    int t = tid + it*256;            // 0..511
    int e = t>>5, pr = t&31;
    int k0 = pr*2;
    int sb = s_src[e]*64 + k0, db = s_dst[e]*64 + k0;
    unsigned usx = *(const unsigned*)&ms_v[0*VPLU+sb];
    unsigned usy = *(const unsigned*)&ms_v[1*VPLU+sb];
    unsigned usz = *(const unsigned*)&ms_v[2*VPLU+sb];
    unsigned udx = *(const unsigned*)&md_v[0*VPLU+db];
    unsigned udy = *(const unsigned*)&md_v[1*VPLU+db];
    unsigned udz = *(const unsigned*)&md_v[2*VPLU+db];
    unsigned uw3 = *(const unsigned*)&sw_v[e*192 + k0];
    unsigned uw4 = *(const unsigned*)&sw_v[e*192 + 64 + k0];
    unsigned uw5 = *(const unsigned*)&sw_v[e*192 + 128 + k0];
    float ex1 = s_e1[0+e], ey1 = s_e1[16+e], ez1 = s_e1[32+e];
    float e0 = s_e0[e];
    float vx0 = lo16f(usx)+lo16f(udx), vx1 = hi16f(usx)+hi16f(udx);
    float vy0 = lo16f(usy)+lo16f(udy), vy1 = hi16f(usy)+hi16f(udy);
    float vz0 = lo16f(usz)+lo16f(udz), vz1 = hi16f(usz)+hi16f(udz);
    float d0 = vx0*ex1 + vy0*ey1 + vz0*ez1;
    float d1 = vx1*ex1 + vy1*ey1 + vz1*ez1;
    *(unsigned*)&ads[e*200+128+k0] =
        cvtpk(lo16f(uw4)*d0*INV_SQRT3f, hi16f(uw4)*d1*INV_SQRT3f);
    float w30 = lo16f(uw3)*e0, w31 = hi16f(uw3)*e0;
    float w50 = lo16f(uw5)*INV_SQRT2f, w51 = hi16f(uw5)*INV_SQRT2f;
    *(unsigned*)&advb[0*2176 + e*136 + k0] = cvtpk(w30*vx0, w31*vx1);
    *(unsigned*)&advb[1*2176 + e*136 + k0] = cvtpk(w30*vy0, w31*vy1);
    *(unsigned*)&advb[2*2176 + e*136 + k0] = cvtpk(w30*vz0, w31*vz1);
    *(unsigned*)&advb[0*2176 + e*136 + 64+k0] =
        cvtpk(w50*(vy0*ez1 - vz0*ey1), w51*(vy1*ez1 - vz1*ey1));
    *(unsigned*)&advb[1*2176 + e*136 + 64+k0] =
        cvtpk(w50*(vz0*ex1 - vx0*ez1), w51*(vz1*ex1 - vx1*ez1));
    *(unsigned*)&advb[2*2176 + e*136 + 64+k0] =
        cvtpk(w50*(vx0*ey1 - vy0*ex1), w51*(vx1*ey1 - vy1*ex1));
  }
  __syncthreads();

  // ---- CD (fused): all MFMAs with fragments in regs, then activations + dtp2 writes
  floatx4 sc0, sc1, sc2, gsa, gb0, gb1, gb2;
  {
    bshort8 fa[6];
    #pragma unroll
    for (int kt=0;kt<6;kt++) fa[kt] = *(const bshort8*)&ads[l15*200 + kt*32 + quad*8];
    // alpha logits + ex/den (run-compressed den atomics over 4 sorted edges)
    #pragma unroll
    for (int t=0;t<2;t++) {
      int h = wave*2 + t;
      int col = h*16 + l15;
      float bb = balpha[col];
      floatx4 acc = {bb,bb,bb,bb};
      #pragma unroll
      for (int kt=0;kt<6;kt++)
        acc = MFMA16(fa[kt], *(const bshort8*)&swz[O_WALP + ((h*6+kt)*64+lane)*8], acc);
      float ad = alpha_dot[col];
      float exv[4];
      #pragma unroll
      for (int r=0;r<4;r++) {
        float p = sleaky(acc[r])*ad;
        p += __shfl_xor(p, 1);
        p += __shfl_xor(p, 2);
        p += __shfl_xor(p, 4);
        p += __shfl_xor(p, 8);
        float ex = __expf(p);
        exv[r] = ex;
        if (l15 == 0) s_ex[(quad*4+r)*8+h] = ex;
      }
      if (l15 == 0) {
        float racc = exv[0]; int cur = s_dst[quad*4];
        #pragma unroll
        for (int r=1;r<4;r++) {
          int d = s_dst[quad*4+r];
          if (d != cur) { atomicAdd(&den[cur*8+h], racc); racc = 0.f; cur = d; }
          racc += exv[r];
        }
        atomicAdd(&den[cur*8+h], racc);
      }
    }
    // scal tiles
    {
      float bb = bact[wave*16 + l15];
      floatx4 a0 = {bb,bb,bb,bb};
      #pragma unroll
      for (int kt=0;kt<6;kt++)
        a0 = MFMA16(fa[kt], *(const bshort8*)&swz[O_WAS + ((wave*6+kt)*64+lane)*8], a0);
      sc0 = a0;
    }
    {
      float bb = bact[(wave+4)*16 + l15];
      floatx4 a1 = {bb,bb,bb,bb};
      #pragma unroll
      for (int kt=0;kt<6;kt++)
        a1 = MFMA16(fa[kt], *(const bshort8*)&swz[O_WAS + (((wave+4)*6+kt)*64+lane)*8], a1);
      sc1 = a1;
    }
    {
      float bb = bact[(wave+8)*16 + l15];
      floatx4 a2 = {bb,bb,bb,bb};
      #pragma unroll
      for (int kt=0;kt<6;kt++)
        a2 = MFMA16(fa[kt], *(const bshort8*)&swz[O_WAS + (((wave+8)*6+kt)*64+lane)*8], a2);
      sc2 = a2;
    }
    bshort8 ft[4];
    #pragma unroll
    for (int kt=0;kt<4;kt++) ft[kt] = *(const bshort8*)&at1[l15*136 + kt*32 + quad*8];
    {
      floatx4 acc = {0.f,0.f,0.f,0.f};
      #pragma unroll
      for (int kt=0;kt<4;kt++)
        acc = MFMA16(ft[kt], *(const bshort8*)&swz[O_WAVT + ((wave*4+kt)*64+lane)*8], acc);
      gsa = acc;
    }
    { // hoist c-invariant WAVB fragments (used 3x)
      bshort8 wb[4];
      #pragma unroll
      for (int kt=0;kt<4;kt++) wb[kt] = *(const bshort8*)&swz[O_WAVB + ((wave*4+kt)*64+lane)*8];
      #pragma unroll
      for (int c=0;c<3;c++) {
        floatx4 acc = {0.f,0.f,0.f,0.f};
        #pragma unroll
        for (int kt=0;kt<4;kt++) {
          bshort8 fb = *(const bshort8*)&advb[c*2176 + l15*136 + kt*32 + quad*8];
          acc = MFMA16(fb, wb[kt], acc);
        }
        if (c==0) gb0 = acc; else if (c==1) gb1 = acc; else gb2 = acc;
      }
    }
  }
  __syncthreads();   // all fragment reads done; safe to overwrite ads/at1/advb

  // ---- CDw: activations + dtp2 writes (w_int pre-folded into dtp2 weights)
  {
    const int k = wave*16 + l15;       // 0..63
    #pragma unroll
    for (int r=0;r<4;r++) {
      int row = quad*4 + r;
      float e0 = s_e0[row];
      { // silu path, tile t0: m = k
        float v = siluf(sc0[r]);
        ads[row*200+k] = f2bf(v*e0);
        at1[row*136+k] = f2bf(v);
      }
      { // silu path, tile t1: m = 64+k
        float v = siluf(sc1[r]);
        ads[row*200+64+k] = f2bf(v*e0);
        at1[row*136+64+k] = f2bf(v);
      }
      { // gated vector path (tile t2 gives scal[128+k])
        float sg = sigm(sc2[r]);
        float gs = gsa[r];
        float ex1 = s_e1[0+row], ey1 = s_e1[16+row], ez1 = s_e1[32+row];
        float v0 = (gs*ex1 + gb0[r])*sg;
        float v1 = (gs*ey1 + gb1[r])*sg;
        float v2 = (gs*ez1 + gb2[r])*sg;
        float d = v0*ex1 + v1*ey1 + v2*ez1;
        ads[row*200+128+k] = f2bf(d);
        advb[0*2176 + row*136 + k] = f2bf(v0*e0);
        advb[1*2176 + row*136 + k] = f2bf(v1*e0);
        advb[2*2176 + row*136 + k] = f2bf(v2*e0);
        advb[0*2176 + row*136 + 64+k] = f2bf(v1*ez1 - v2*ey1);
        advb[1*2176 + row*136 + 64+k] = f2bf(v2*ex1 - v0*ez1);
        advb[2*2176 + row*136 + 64+k] = f2bf(v0*ey1 - v1*ex1);
      }
    }
  }
  __syncthreads();

  // ---- E1: scalar-out MFMAs -> vout staging (x ex). vout aliases sw_v+ads:
  //      barrier between fragment loads and the overwrite.
  {
    bshort8 fa[6];
    #pragma unroll
    for (int kt=0;kt<6;kt++) fa[kt] = *(const bshort8*)&ads[l15*200 + kt*32 + quad*8];
    __syncthreads();   // all lanes' fa loads complete before vout overwrites ads
    #pragma unroll
    for (int t=0;t<2;t++) {
      int h = wave + 4*t;
      float bb = bval[h*16 + l15];
      floatx4 acc = {bb,bb,bb,bb};
      #pragma unroll
      for (int kt=0;kt<6;kt++)
        acc = MFMA16(fa[kt], *(const bshort8*)&swz[O_WVS + ((h*6+kt)*64+lane)*8], acc);
      #pragma unroll
      for (int r=0;r<4;r++) {
        int row = quad*4 + r;
        vout[row*132 + h*16 + l15] = acc[r]*s_ex[row*8+h];
      }
    }
  }
  __syncthreads();

  // ---- F1: 16-edge run-compressed scalar scatter
  if (tid < 128) {
    const int j = tid, h = j>>4, jj = j&15;
    float acc = 0.f; int cur = s_dst[0];
    #pragma unroll
    for (int e = 0; e < 16; ++e) {
      int d = s_dst[e];
      if (d != cur) { atomicAdd(&num[cur*320 + h*40 + jj], acc); acc = 0.f; cur = d; }
      acc += vout[e*132 + j];
    }
    atomicAdd(&num[cur*320 + h*40 + jj], acc);
  }
  __syncthreads();

  // ---- E2: vector MFMAs -> vout staging (x ex); writes stay in [0,12544)
  //      so at1/advb (live fragment sources) are untouched: no extra barrier
  {
    bshort8 ft[4];
    #pragma unroll
    for (int kt=0;kt<4;kt++) ft[kt] = *(const bshort8*)&at1[l15*136 + kt*32 + quad*8];
    floatx4 vsh = {0.f,0.f,0.f,0.f};
    #pragma unroll
    for (int kt=0;kt<4;kt++)
      vsh = MFMA16(ft[kt], *(const bshort8*)&swz[O_WVVT + ((wave*4+kt)*64+lane)*8], vsh);
    const int k = wave*16 + l15;
    const int h = k>>3, q = k&7;
    floatx4 vb0, vb1, vb2;
    { // hoist c-invariant WVVB fragments (used 3x)
      bshort8 wb[4];
      #pragma unroll
      for (int kt=0;kt<4;kt++) wb[kt] = *(const bshort8*)&swz[O_WVVB + ((wave*4+kt)*64+lane)*8];
      #pragma unroll
      for (int c=0;c<3;c++) {
        floatx4 acc = {0.f,0.f,0.f,0.f};
        #pragma unroll
        for (int kt=0;kt<4;kt++) {
          bshort8 fb = *(const bshort8*)&advb[c*2176 + l15*136 + kt*32 + quad*8];
          acc = MFMA16(fb, wb[kt], acc);
        }
        if (c==0) vb0 = acc; else if (c==1) vb1 = acc; else vb2 = acc;
      }
    }
    #pragma unroll
    for (int r=0;r<4;r++) {
      int row = quad*4 + r;
      float exr = s_ex[row*8+h];
      vout[row*194 + h*24 + q*3 + 0] = (vb0[r] + s_e1[0*16+row]*vsh[r])*exr;
      vout[row*194 + h*24 + q*3 + 1] = (vb1[r] + s_e1[1*16+row]*vsh[r])*exr;
      vout[row*194 + h*24 + q*3 + 2] = (vb2[r] + s_e1[2*16+row]*vsh[r])*exr;
    }
  }
  __syncthreads();

  // ---- F2: 16-edge run-compressed vector scatter
  if (tid < 192) {
    const int jj = tid;
    const int h = jj/24, rr = jj - h*24;
    float acc = 0.f; int cur = s_dst[0];
    #pragma unroll
    for (int e = 0; e < 16; ++e) {
      int d = s_dst[e];
      if (d != cur) { atomicAdd(&num[cur*320 + h*40 + 16 + rr], acc); acc = 0.f; cur = d; }
      acc += vout[e*194 + jj];
    }
    atomicAdd(&num[cur*320 + h*40 + 16 + rr], acc);
  }
}

// ---------------------------------------------------------------- node post (fp32 GEMV, 16 nodes/block)
__global__ __launch_bounds__(256) void node_post(
    const float* __restrict__ num, const float* __restrict__ den,
    const float* __restrict__ Wproj_s, const float* __restrict__ bproj,
    const float* __restrict__ Wproj_v, float* __restrict__ out) {
  __shared__ __align__(16) float s_ns[128*16];
  __shared__ __align__(16) float s_nv[192*16];
  const int tid = threadIdx.x;
  const int n0 = blockIdx.x*16;
  for (int idx = tid; idx < 16*320; idx += 256) {
    int n = idx/320, j = idx - n*320;
    int h = j/40, r = j - h*40;
    float a = num[(n0+n)*320+j] / (den[(n0+n)*8+h] + 1e-16f);
    if (r < 16) s_ns[(h*16+r)*16+n] = a;
    else        s_nv[(h*24 + (r-16))*16+n] = a;
  }
  __syncthreads();
  {
    int g = tid>>7, j = tid&127;
    float acc[8]; float b = bproj[j];
    #pragma unroll
    for (int i=0;i<8;i++) acc[i]=b;
    for (int k=0;k<128;k++) {
      float wv = Wproj_s[k*128+j];
      float4 a0 = *(const float4*)&s_ns[k*16+g*8];
      float4 a1 = *(const float4*)&s_ns[k*16+g*8+4];
      acc[0]+=a0.x*wv; acc[1]+=a0.y*wv; acc[2]+=a0.z*wv; acc[3]+=a0.w*wv;
      acc[4]+=a1.x*wv; acc[5]+=a1.y*wv; acc[6]+=a1.z*wv; acc[7]+=a1.w*wv;
    }
    #pragma unroll
    for (int i=0;i<8;i++) out[(n0+g*8+i)*320 + j] = acc[i];
  }
  if (tid < 192) {
    int c = tid>>6, k = tid&63;
    #pragma unroll
    for (int half=0; half<2; ++half) {
      float acc[8];
      #pragma unroll
      for (int e=0;e<8;e++) acc[e]=0.f;
      for (int m=0;m<64;m++) {
        float wv = Wproj_v[m*64+k];
        float4 v0 = *(const float4*)&s_nv[(m*3+c)*16 + half*8];
        float4 v1 = *(const float4*)&s_nv[(m*3+c)*16 + half*8 + 4];
        acc[0]+=v0.x*wv; acc[1]+=v0.y*wv; acc[2]+=v0.z*wv; acc[3]+=v0.w*wv;
        acc[4]+=v1.x*wv; acc[5]+=v1.y*wv; acc[6]+=v1.z*wv; acc[7]+=v1.w*wv;
      }
      #pragma unroll
      for (int e=0;e<8;e++) out[(n0+half*8+e)*320 + 128 + k*3 + c] = acc[e];
    }
  }
}

// ---------------------------------------------------------------- launch
extern "C" void kernel_launch(void* const* d_in, const int* in_sizes, int n_in,
                              void* d_out, int out_size, void* d_ws, size_t ws_size,
                              hipStream_t stream) {
  (void)in_sizes; (void)n_in; (void)out_size; (void)ws_size;
  const float* node_input = (const float*)d_in[0];
  const int*   esrc       = (const int*)d_in[1];
  const int*   edst       = (const int*)d_in[2];
  const float* eattr      = (const float*)d_in[3];
  const float* escal      = (const float*)d_in[4];
  const float* Wsrc_s     = (const float*)d_in[5];
  const float* Wsrc_v     = (const float*)d_in[6];
  const float* bsrc       = (const float*)d_in[7];
  const float* Wdst_s     = (const float*)d_in[8];
  const float* Wdst_v     = (const float*)d_in[9];
  const float* rad_W1     = (const float*)d_in[10];
  const float* rad_b1     = (const float*)d_in[11];
  const float* rad_W2     = (const float*)d_in[12];
  const float* rad_off    = (const float*)d_in[13];
  const float* Wact_s     = (const float*)d_in[14];
  const float* bact       = (const float*)d_in[15];
  const float* Wact_v     = (const float*)d_in[16];
  const float* Walpha     = (const float*)d_in[17];
  const float* balpha     = (const float*)d_in[18];
  const float* w_int      = (const float*)d_in[19];
  const float* Wval_s     = (const float*)d_in[20];
  const float* bval       = (const float*)d_in[21];
  const float* Wval_v     = (const float*)d_in[22];
  const float* alpha_dot  = (const float*)d_in[23];
  const float* Wproj_s    = (const float*)d_in[24];
  const float* bproj      = (const float*)d_in[25];
  const float* Wproj_v    = (const float*)d_in[26];
  float* out = (float*)d_out;

  char* wsb = (char*)d_ws;
  unsigned short* ms_s16 = (unsigned short*)(wsb);              //  2,560,000 B
  unsigned short* md_s16 = (unsigned short*)(wsb + 2560000);    //  2,560,000 B
  unsigned short* ms_v16 = (unsigned short*)(wsb + 5120000);    //  3,840,000 B (planar)
  unsigned short* md_v16 = (unsigned short*)(wsb + 8960000);    //  3,840,000 B
  float* den             = (float*)(wsb + 12800000);            //    320,000 B
  float* num             = (float*)(wsb + 13120000);            // 12,800,000 B
  unsigned short* swz    = (unsigned short*)(wsb + 25920000);   //    299,008 B
  int* cnt  = (int*)(wsb + 26220032);                           //     40,000 B
  int* offs = (int*)(wsb + 26260032);                           //     40,000 B
  int* perm = (int*)(wsb + 26300032);                           //    640,000 B -> ~26.9 MB

  k_pre_all<<<3375, 256, 0, stream>>>(node_input, Wsrc_s, Wsrc_v, bsrc, Wdst_s, Wdst_v,
                                      ms_s16, md_s16, ms_v16, md_v16,
                                      rad_W1, rad_W2, Wact_s, Wact_v, Wval_s, Wval_v,
                                      Walpha, w_int, swz, num, den, cnt);
  k_hist<<<625, 256, 0, stream>>>(edst, cnt);
  k_scan<<<1, 256, 0, stream>>>(cnt, offs);
  k_scatter<<<625, 256, 0, stream>>>(edst, offs, perm);
  e_all<<<10000, 256, 0, stream>>>(ms_s16, md_s16, ms_v16, md_v16, esrc, edst, perm, eattr, escal,
                                   rad_b1, rad_off, bact, bval,
                                   balpha, alpha_dot, swz, den, num);
  node_post<<<625, 256, 0, stream>>>(num, den, Wproj_s, bproj, Wproj_v, out);
}

// Round 8
// 375.810 us; speedup vs baseline: 1.1792x; 1.0172x over previous
//
#include <hip/hip_runtime.h>

#define NN 10000
#define NE 160000
#define INV_SQRT3f 0.57735026918962576f
#define INV_SQRT2f 0.70710678118654752f
#define VPLU 640000   // vector plane length (NN*64 ushorts)

typedef short bshort8 __attribute__((ext_vector_type(8)));
typedef float floatx4 __attribute__((ext_vector_type(4)));
#define MFMA16(a,b,c) __builtin_amdgcn_mfma_f32_16x16x32_bf16((a),(b),(c),0,0,0)

__device__ __forceinline__ float sigm(float x){ return 1.f/(1.f+__expf(-x)); }
__device__ __forceinline__ float siluf(float x){ return x*sigm(x); }
__device__ __forceinline__ float sleaky(float x){ return 0.6f*x + 0.4f*x*(2.f*sigm(x)-1.f); }
// round-half-up bf16 convert: 2 VALU ops vs 5 for RNE
__device__ __forceinline__ unsigned short f2bf(float f){
  return (unsigned short)((__float_as_uint(f) + 0x8000u)>>16);
}
__device__ __forceinline__ float bf2f(unsigned short h){
  return __uint_as_float(((unsigned)h)<<16);
}
// packed 2xbf16 convert (RNE), 1 VALU op for 2 values
__device__ __forceinline__ unsigned cvtpk(float lo, float hi){
  unsigned r;
  asm("v_cvt_pk_bf16_f32 %0, %1, %2" : "=v"(r) : "v"(lo), "v"(hi));
  return r;
}
// unpack 2xbf16 from a dword: 1 VALU op each
__device__ __forceinline__ float lo16f(unsigned u){ return __uint_as_float(u<<16); }
__device__ __forceinline__ float hi16f(unsigned u){ return __uint_as_float(u & 0xffff0000u); }

// swizzled-weight segment offsets (in ushorts)
#define O_W1   0
#define O_W2   2048
#define O_WAS  30720
#define O_WAVT 67584
#define O_WAVB 75776
#define O_WVS  83968
#define O_WVVT 108544
#define O_WVVB 116736
#define O_WALP 124928
#define SWZ_TOTAL 149504

// ---------------------------------------------------------------- merged pre-pass:
//  blocks [0,625): node_pre, 16 nodes/block (fp32 GEMV -> bf16 planar staging)
//  blocks [625,1209): weight pre-swizzle (w_int/INV_SQRT* folded into dtp2 weights)
//  blocks [1209,3375): grid-stride zero of num/den/cnt/rank
__global__ __launch_bounds__(256) void k_pre_all(
    const float* __restrict__ x,
    const float* __restrict__ Wsrc_s, const float* __restrict__ Wsrc_v,
    const float* __restrict__ bsrc,
    const float* __restrict__ Wdst_s, const float* __restrict__ Wdst_v,
    unsigned short* __restrict__ ms_s, unsigned short* __restrict__ md_s,
    unsigned short* __restrict__ ms_v, unsigned short* __restrict__ md_v,
    const float* __restrict__ W1, const float* __restrict__ W2,
    const float* __restrict__ WAs, const float* __restrict__ WAv,
    const float* __restrict__ WVs, const float* __restrict__ WVv,
    const float* __restrict__ WAl, const float* __restrict__ w_int,
    unsigned short* __restrict__ swz,
    float* __restrict__ num, float* __restrict__ den,
    int* __restrict__ cnt, int* __restrict__ rank) {
  __shared__ __align__(16) float s_s[128*16];
  __shared__ __align__(16) float s_v[192*16];
  const int tid = threadIdx.x;
  const int b = blockIdx.x;
  if (b >= 1209) {            // ---- init branch
    int base = (b-1209)*256 + tid;      // [0, 554496)
    float4 z = {0.f,0.f,0.f,0.f};
    for (int i = base; i < 800000; i += 554496) ((float4*)num)[i] = z;
    if (base < 20000) ((float4*)den)[base] = z;
    if (base < 10000) { cnt[base] = 0; rank[base] = 0; }
    return;
  }
  if (b >= 625) {             // ---- weight swizzle branch
    int s = (b-625)*256 + tid;
    if (s >= SWZ_TOTAL) return;
    const float* src; int base, N, KT, rowOff;
    if      (s < 2048)  { base=O_W1;   src=W1;  N=64;  KT=1; rowOff=0; }
    else if (s < 30720) { base=O_W2;   src=W2;  N=448; KT=2; rowOff=0; }
    else if (s < 67584) { base=O_WAS;  src=WAs; N=192; KT=6; rowOff=0; }
    else if (s < 75776) { base=O_WAVT; src=WAv; N=64;  KT=4; rowOff=0; }
    else if (s < 83968) { base=O_WAVB; src=WAv; N=64;  KT=4; rowOff=128; }
    else if (s < 108544){ base=O_WVS;  src=WVs; N=128; KT=6; rowOff=0; }
    else if (s < 116736){ base=O_WVVT; src=WVv; N=64;  KT=4; rowOff=0; }
    else if (s < 124928){ base=O_WVVB; src=WVv; N=64;  KT=4; rowOff=128; }
    else                { base=O_WALP; src=WAl; N=128; KT=6; rowOff=0; }
    int loc = s - base;
    int j = loc & 7, l = (loc>>3)&63, kt = (loc>>9)%KT, nt = loc/(512*KT);
    int row = kt*32 + (l>>4)*8 + j + rowOff;
    int col = nt*16 + (l&15);
    // fold w_int (and the dtp2 INV_SQRT* constants) into the dtp2 weights
    float scl = 1.f;
    if      (base == O_WVS)  scl = (row < 128) ? w_int[row] : w_int[192+row]*INV_SQRT3f;
    else if (base == O_WVVT) scl = w_int[128+row];
    else if (base == O_WVVB) scl = (row < 192) ? w_int[128+row] : w_int[192+row]*INV_SQRT2f;
    swz[s] = f2bf(src[row*N + col] * scl);
    return;
  }
  // ---- node_pre branch: 16 nodes per block, planar vector staging
  const int n0 = b*16;
  for (int idx = tid; idx < 16*320; idx += 256) {
    int n = idx/320, d = idx - n*320;
    float val = x[(n0+n)*320 + d];
    if (d < 128) s_s[d*16+n] = val;
    else         s_v[(d-128)*16+n] = val;
  }
  __syncthreads();
  {
    int g = tid>>7, j = tid&127;    // g selects nodes g*8..g*8+7
    float accs[8], accd[8];
    float bb = bsrc[j];
    #pragma unroll
    for (int i=0;i<8;i++){ accs[i]=bb; accd[i]=0.f; }
    for (int k=0;k<128;k++) {
      float w1 = Wsrc_s[k*128+j], w2 = Wdst_s[k*128+j];
      float4 a0 = *(const float4*)&s_s[k*16+g*8];
      float4 a1 = *(const float4*)&s_s[k*16+g*8+4];
      accs[0]+=a0.x*w1; accs[1]+=a0.y*w1; accs[2]+=a0.z*w1; accs[3]+=a0.w*w1;
      accs[4]+=a1.x*w1; accs[5]+=a1.y*w1; accs[6]+=a1.z*w1; accs[7]+=a1.w*w1;
      accd[0]+=a0.x*w2; accd[1]+=a0.y*w2; accd[2]+=a0.z*w2; accd[3]+=a0.w*w2;
      accd[4]+=a1.x*w2; accd[5]+=a1.y*w2; accd[6]+=a1.z*w2; accd[7]+=a1.w*w2;
    }
    #pragma unroll
    for (int i=0;i<8;i++){ int n=n0+g*8+i; ms_s[n*128+j]=f2bf(accs[i]); md_s[n*128+j]=f2bf(accd[i]); }
  }
  if (tid < 192) {
    int c = tid>>6, k = tid&63;
    #pragma unroll
    for (int half=0; half<2; ++half) {
      float accs[8], accd[8];
      #pragma unroll
      for (int e=0;e<8;e++){ accs[e]=0.f; accd[e]=0.f; }
      for (int m=0;m<64;m++) {
        float w1 = Wsrc_v[m*64+k], w2 = Wdst_v[m*64+k];
        float4 v0 = *(const float4*)&s_v[(m*3+c)*16 + half*8];
        float4 v1 = *(const float4*)&s_v[(m*3+c)*16 + half*8 + 4];
        accs[0]+=v0.x*w1; accs[1]+=v0.y*w1; accs[2]+=v0.z*w1; accs[3]+=v0.w*w1;
        accs[4]+=v1.x*w1; accs[5]+=v1.y*w1; accs[6]+=v1.z*w1; accs[7]+=v1.w*w1;
        accd[0]+=v0.x*w2; accd[1]+=v0.y*w2; accd[2]+=v0.z*w2; accd[3]+=v0.w*w2;
        accd[4]+=v1.x*w2; accd[5]+=v1.y*w2; accd[6]+=v1.z*w2; accd[7]+=v1.w*w2;
      }
      #pragma unroll
      for (int e=0;e<8;e++){
        int n = n0 + half*8 + e;
        ms_v[c*VPLU + n*64 + k] = f2bf(accs[e]);
        md_v[c*VPLU + n*64 + k] = f2bf(accd[e]);
      }
    }
  }
}

// ---------------------------------------------------------------- counting sort of edges by dst
__global__ __launch_bounds__(256) void k_hist(const int* __restrict__ edst,
                                              int* __restrict__ cnt) {
  int e = blockIdx.x*256 + threadIdx.x;
  if (e < NE) atomicAdd(&cnt[edst[e]], 1);
}

// merged scan+scatter: every block redundantly computes the full exclusive scan
// of cnt in LDS (parallel across CUs, no cross-block dependency), then scatters
// its 256 edges at pos = scan[dst] + global-atomic-rank[dst]. Deletes the
// serial 1-block k_scan launch + one launch boundary.
__global__ __launch_bounds__(256) void k_scan_scatter(
    const int* __restrict__ cnt, int* __restrict__ rank,
    const int* __restrict__ edst, int* __restrict__ perm) {
  __shared__ int sc[10240];
  __shared__ int wsum[4];
  const int tid = threadIdx.x;
  const int lane = tid & 63, wave = tid >> 6;
  for (int i = tid; i < 10240; i += 256) sc[i] = (i < NN) ? cnt[i] : 0;
  __syncthreads();
  int v[40]; int s = 0;
  #pragma unroll
  for (int j=0;j<40;j++){ v[j] = sc[tid*40+j]; s += v[j]; }
  int incl = s;
  #pragma unroll
  for (int d=1; d<64; d<<=1) { int t = __shfl_up(incl, d, 64); if (lane>=d) incl += t; }
  if (lane==63) wsum[wave] = incl;
  __syncthreads();
  int wbase = 0;
  for (int w=0; w<wave; ++w) wbase += wsum[w];
  int excl = wbase + incl - s;
  // each thread owns sc[tid*40 .. tid*40+39]: safe to overwrite its own slice
  #pragma unroll
  for (int j=0;j<40;j++){ sc[tid*40+j] = excl; excl += v[j]; }
  __syncthreads();
  int e = blockIdx.x*256 + tid;
  if (e < NE) {
    int d = edst[e];
    int r = atomicAdd(&rank[d], 1);
    perm[sc[d] + r] = e;
  }
}

// ---------------------------------------------------------------- fused edge pass
// r7 structure (validated: 193us, FETCH 71MB, WRITE 45MB), frozen except the
// B-vector stage: k-quads (16 threads/edge, dwordx2 loads, one pass) instead of
// k-pairs (32 threads/edge, two passes) -- same 128B/edge/plane segments, fewer
// load/address instructions and per-edge scalar reloads.
__global__ __launch_bounds__(256, 5) void e_all(
    const unsigned short* __restrict__ ms_s, const unsigned short* __restrict__ md_s,
    const unsigned short* __restrict__ ms_v, const unsigned short* __restrict__ md_v,
    const int* __restrict__ esrc, const int* __restrict__ edst,
    const int* __restrict__ perm,
    const float* __restrict__ eattr, const float* __restrict__ escal,
    const float* __restrict__ rad_b1, const float* __restrict__ rad_off,
    const float* __restrict__ bact,
    const float* __restrict__ bval,
    const float* __restrict__ balpha, const float* __restrict__ alpha_dot,
    const unsigned short* __restrict__ swz,
    float* __restrict__ den, float* __restrict__ num) {
  __shared__ __align__(16) char smem[30912];
  unsigned short* sw_v = (unsigned short*)smem;            // 16x192 (w3|w4|w5) [0,6144)
  float* vout          = (float*)smem;                     // E1: 16x132, E2: 16x194 f32 [0,12544)
  unsigned short* ads  = (unsigned short*)(smem+6144);     // 16x200 (ds / vs) [6144,12544)
  unsigned short* at1  = (unsigned short*)(smem+12544);    // 16x136 (t1 / t2)
  unsigned short* advb = (unsigned short*)(smem+16896);    // 3x16x136 (dvB / vvB)
  unsigned short* aes  = (unsigned short*)(smem+16896);    // alias (dead pre-B)
  unsigned short* ah   = (unsigned short*)(smem+19456);    // alias (dead pre-B)
  float* s_e0 = (float*)(smem+29952);
  float* s_e1 = (float*)(smem+30016);
  float* s_ex = (float*)(smem+30208);
  int* s_eid  = (int*)(smem+30720);
  int* s_src  = (int*)(smem+30784);
  int* s_dst  = (int*)(smem+30848);
  const int tid  = threadIdx.x;
  const int lane = tid & 63, wave = tid >> 6;
  const int quad = lane >> 4, l15 = lane & 15;
  // bijective XCD-chunk swizzle (10000 = 8*1250)
  const int bswz = (blockIdx.x & 7)*1250 + (blockIdx.x >> 3);
  const int eb = bswz*16;

  if (tid < 16) {
    int eid = perm[eb+tid];
    s_eid[tid] = eid; s_src[tid] = esrc[eid]; s_dst[tid] = edst[eid];
  }
  __syncthreads();
  if (tid >= 64 && tid < 128) {
    int t = tid-64, e = t>>2, q = t&3;
    float a = eattr[s_eid[e]*4+q];
    if (q == 0) s_e0[e] = a; else s_e1[(q-1)*16+e] = a;
  }
  { // packed escal staging: 256 threads x 2 values
    int e = tid>>4, i0 = (tid&15)*2;
    float2 es = *(const float2*)&escal[s_eid[e]*32+i0];
    *(unsigned*)&aes[e*40+i0] = cvtpk(es.x, es.y);
  }
  __syncthreads();

  // ---- A1: h = silu(escal@W1+b1)
  {
    int nt = wave, col = nt*16 + l15;
    bshort8 a = *(const bshort8*)&aes[l15*40 + quad*8];
    bshort8 b = *(const bshort8*)&swz[O_W1 + (nt*64 + lane)*8];
    float bb = rad_b1[col];
    floatx4 acc = {bb,bb,bb,bb};
    acc = MFMA16(a, b, acc);
    #pragma unroll
    for (int r=0;r<4;r++) ah[(quad*4+r)*72 + col] = f2bf(siluf(acc[r]));
  }
  __syncthreads();

  // ---- A2': w tiles + fused B-scalar.
  //   w1/w2 (cols 0..255): lane holds w1[e][m] and w2[e][m] for the SAME (e,m)
  //   by pairing tiles nt and nt+8 -> one msgs gather feeds ads and at1.
  //   w3/w4/w5 (cols 256..447): store bf16 w to sw_v for the B-vector stage.
  {
    bshort8 ha0 = *(const bshort8*)&ah[l15*72 + quad*8];
    bshort8 ha1 = *(const bshort8*)&ah[l15*72 + 32 + quad*8];
    int src_[4], dst_[4];
    #pragma unroll
    for (int r=0;r<4;r++){ int e=quad*4+r; src_[r]=s_src[e]; dst_[r]=s_dst[e]; }
    #pragma unroll
    for (int p=0;p<2;p++) {
      int nt1 = wave*2+p, nt2 = nt1+8;
      int m = nt1*16 + l15;
      float o1 = rad_off[m], o2 = rad_off[128+m];
      floatx4 a1 = {o1,o1,o1,o1}, a2 = {o2,o2,o2,o2};
      a1 = MFMA16(ha0, *(const bshort8*)&swz[O_W2 + ((nt1*2+0)*64+lane)*8], a1);
      a1 = MFMA16(ha1, *(const bshort8*)&swz[O_W2 + ((nt1*2+1)*64+lane)*8], a1);
      a2 = MFMA16(ha0, *(const bshort8*)&swz[O_W2 + ((nt2*2+0)*64+lane)*8], a2);
      a2 = MFMA16(ha1, *(const bshort8*)&swz[O_W2 + ((nt2*2+1)*64+lane)*8], a2);
      #pragma unroll
      for (int r=0;r<4;r++) {
        int e = quad*4+r;
        float msgs = bf2f(ms_s[src_[r]*128+m]) + bf2f(md_s[dst_[r]*128+m]);
        ads[e*200+m] = f2bf(a1[r]*msgs*s_e0[e]);
        at1[e*136+m] = f2bf(a2[r]*msgs);
      }
    }
    #pragma unroll
    for (int q=0;q<3;q++) {
      int nt = 16 + wave*3 + q, col = nt*16 + l15;
      float o = rad_off[col];
      floatx4 acc = {o,o,o,o};
      acc = MFMA16(ha0, *(const bshort8*)&swz[O_W2 + ((nt*2+0)*64+lane)*8], acc);
      acc = MFMA16(ha1, *(const bshort8*)&swz[O_W2 + ((nt*2+1)*64+lane)*8], acc);
      #pragma unroll
      for (int r=0;r<4;r++) sw_v[(quad*4+r)*192 + (col-256)] = f2bf(acc[r]);
    }
  }
  __syncthreads();

  // ---- B-vector: dtp1 vector part, k-quads (16 threads/edge, dwordx2 loads)
  {
    const int e = tid>>4, k0 = (tid&15)*4;
    int sb = s_src[e]*64 + k0, db = s_dst[e]*64 + k0;
    uint2 usx = *(const uint2*)&ms_v[0*VPLU+sb];
    uint2 usy = *(const uint2*)&ms_v[1*VPLU+sb];
    uint2 usz = *(const uint2*)&ms_v[2*VPLU+sb];
    uint2 udx = *(const uint2*)&md_v[0*VPLU+db];
    uint2 udy = *(const uint2*)&md_v[1*VPLU+db];
    uint2 udz = *(const uint2*)&md_v[2*VPLU+db];
    uint2 uw3 = *(const uint2*)&sw_v[e*192 + k0];
    uint2 uw4 = *(const uint2*)&sw_v[e*192 + 64 + k0];
    uint2 uw5 = *(const uint2*)&sw_v[e*192 + 128 + k0];
    const float ex1 = s_e1[0+e], ey1 = s_e1[16+e], ez1 = s_e1[32+e];
    const float e0 = s_e0[e];
    unsigned ax[2]={usx.x,usx.y}, ay[2]={usy.x,usy.y}, az[2]={usz.x,usz.y};
    unsigned bx[2]={udx.x,udx.y}, by[2]={udy.x,udy.y}, bz[2]={udz.x,udz.y};
    unsigned w3[2]={uw3.x,uw3.y}, w4[2]={uw4.x,uw4.y}, w5[2]={uw5.x,uw5.y};
    #pragma unroll
    for (int p=0;p<2;p++) {
      const int kk = k0 + 2*p;
      float vx0 = lo16f(ax[p])+lo16f(bx[p]), vx1 = hi16f(ax[p])+hi16f(bx[p]);
      float vy0 = lo16f(ay[p])+lo16f(by[p]), vy1 = hi16f(ay[p])+hi16f(by[p]);
      float vz0 = lo16f(az[p])+lo16f(bz[p]), vz1 = hi16f(az[p])+hi16f(bz[p]);
      float d0 = vx0*ex1 + vy0*ey1 + vz0*ez1;
      float d1 = vx1*ex1 + vy1*ey1 + vz1*ez1;
      *(unsigned*)&ads[e*200+128+kk] =
          cvtpk(lo16f(w4[p])*d0*INV_SQRT3f, hi16f(w4[p])*d1*INV_SQRT3f);
      float w30 = lo16f(w3[p])*e0, w31 = hi16f(w3[p])*e0;
      float w50 = lo16f(w5[p])*INV_SQRT2f, w51 = hi16f(w5[p])*INV_SQRT2f;
      *(unsigned*)&advb[0*2176 + e*136 + kk] = cvtpk(w30*vx0, w31*vx1);
      *(unsigned*)&advb[1*2176 + e*136 + kk] = cvtpk(w30*vy0, w31*vy1);
      *(unsigned*)&advb[2*2176 + e*136 + kk] = cvtpk(w30*vz0, w31*vz1);
      *(unsigned*)&advb[0*2176 + e*136 + 64+kk] =
          cvtpk(w50*(vy0*ez1 - vz0*ey1), w51*(vy1*ez1 - vz1*ey1));
      *(unsigned*)&advb[1*2176 + e*136 + 64+kk] =
          cvtpk(w50*(vz0*ex1 - vx0*ez1), w51*(vz1*ex1 - vx1*ez1));
      *(unsigned*)&advb[2*2176 + e*136 + 64+kk] =
          cvtpk(w50*(vx0*ey1 - vy0*ex1), w51*(vx1*ey1 - vy1*ex1));
    }
  }
  __syncthreads();

  // ---- CD (fused): all MFMAs with fragments in regs, then activations + dtp2 writes
  floatx4 sc0, sc1, sc2, gsa, gb0, gb1, gb2;
  {
    bshort8 fa[6];
    #pragma unroll
    for (int kt=0;kt<6;kt++) fa[kt] = *(const bshort8*)&ads[l15*200 + kt*32 + quad*8];
    // alpha logits + ex/den (run-compressed den atomics over 4 sorted edges)
    #pragma unroll
    for (int t=0;t<2;t++) {
      int h = wave*2 + t;
      int col = h*16 + l15;
      float bb = balpha[col];
      floatx4 acc = {bb,bb,bb,bb};
      #pragma unroll
      for (int kt=0;kt<6;kt++)
        acc = MFMA16(fa[kt], *(const bshort8*)&swz[O_WALP + ((h*6+kt)*64+lane)*8], acc);
      float ad = alpha_dot[col];
      float exv[4];
      #pragma unroll
      for (int r=0;r<4;r++) {
        float p = sleaky(acc[r])*ad;
        p += __shfl_xor(p, 1);
        p += __shfl_xor(p, 2);
        p += __shfl_xor(p, 4);
        p += __shfl_xor(p, 8);
        float ex = __expf(p);
        exv[r] = ex;
        if (l15 == 0) s_ex[(quad*4+r)*8+h] = ex;
      }
      if (l15 == 0) {
        float racc = exv[0]; int cur = s_dst[quad*4];
        #pragma unroll
        for (int r=1;r<4;r++) {
          int d = s_dst[quad*4+r];
          if (d != cur) { atomicAdd(&den[cur*8+h], racc); racc = 0.f; cur = d; }
          racc += exv[r];
        }
        atomicAdd(&den[cur*8+h], racc);
      }
    }
    // scal tiles
    {
      float bb = bact[wave*16 + l15];
      floatx4 a0 = {bb,bb,bb,bb};
      #pragma unroll
      for (int kt=0;kt<6;kt++)
        a0 = MFMA16(fa[kt], *(const bshort8*)&swz[O_WAS + ((wave*6+kt)*64+lane)*8], a0);
      sc0 = a0;
    }
    {
      float bb = bact[(wave+4)*16 + l15];
      floatx4 a1 = {bb,bb,bb,bb};
      #pragma unroll
      for (int kt=0;kt<6;kt++)
        a1 = MFMA16(fa[kt], *(const bshort8*)&swz[O_WAS + (((wave+4)*6+kt)*64+lane)*8], a1);
      sc1 = a1;
    }
    {
      float bb = bact[(wave+8)*16 + l15];
      floatx4 a2 = {bb,bb,bb,bb};
      #pragma unroll
      for (int kt=0;kt<6;kt++)
        a2 = MFMA16(fa[kt], *(const bshort8*)&swz[O_WAS + (((wave+8)*6+kt)*64+lane)*8], a2);
      sc2 = a2;
    }
    bshort8 ft[4];
    #pragma unroll
    for (int kt=0;kt<4;kt++) ft[kt] = *(const bshort8*)&at1[l15*136 + kt*32 + quad*8];
    {
      floatx4 acc = {0.f,0.f,0.f,0.f};
      #pragma unroll
      for (int kt=0;kt<4;kt++)
        acc = MFMA16(ft[kt], *(const bshort8*)&swz[O_WAVT + ((wave*4+kt)*64+lane)*8], acc);
      gsa = acc;
    }
    { // hoist c-invariant WAVB fragments (used 3x)
      bshort8 wb[4];
      #pragma unroll
      for (int kt=0;kt<4;kt++) wb[kt] = *(const bshort8*)&swz[O_WAVB + ((wave*4+kt)*64+lane)*8];
      #pragma unroll
      for (int c=0;c<3;c++) {
        floatx4 acc = {0.f,0.f,0.f,0.f};
        #pragma unroll
        for (int kt=0;kt<4;kt++) {
          bshort8 fb = *(const bshort8*)&advb[c*2176 + l15*136 + kt*32 + quad*8];
          acc = MFMA16(fb, wb[kt], acc);
        }
        if (c==0) gb0 = acc; else if (c==1) gb1 = acc; else gb2 = acc;
      }
    }
  }
  __syncthreads();   // all fragment reads done; safe to overwrite ads/at1/advb

  // ---- CDw: activations + dtp2 writes (w_int pre-folded into dtp2 weights)
  {
    const int k = wave*16 + l15;       // 0..63
    #pragma unroll
    for (int r=0;r<4;r++) {
      int row = quad*4 + r;
      float e0 = s_e0[row];
      { // silu path, tile t0: m = k
        float v = siluf(sc0[r]);
        ads[row*200+k] = f2bf(v*e0);
        at1[row*136+k] = f2bf(v);
      }
      { // silu path, tile t1: m = 64+k
        float v = siluf(sc1[r]);
        ads[row*200+64+k] = f2bf(v*e0);
        at1[row*136+64+k] = f2bf(v);
      }
      { // gated vector path (tile t2 gives scal[128+k])
        float sg = sigm(sc2[r]);
        float gs = gsa[r];
        float ex1 = s_e1[0+row], ey1 = s_e1[16+row], ez1 = s_e1[32+row];
        float v0 = (gs*ex1 + gb0[r])*sg;
        float v1 = (gs*ey1 + gb1[r])*sg;
        float v2 = (gs*ez1 + gb2[r])*sg;
        float d = v0*ex1 + v1*ey1 + v2*ez1;
        ads[row*200+128+k] = f2bf(d);
        advb[0*2176 + row*136 + k] = f2bf(v0*e0);
        advb[1*2176 + row*136 + k] = f2bf(v1*e0);
        advb[2*2176 + row*136 + k] = f2bf(v2*e0);
        advb[0*2176 + row*136 + 64+k] = f2bf(v1*ez1 - v2*ey1);
        advb[1*2176 + row*136 + 64+k] = f2bf(v2*ex1 - v0*ez1);
        advb[2*2176 + row*136 + 64+k] = f2bf(v0*ey1 - v1*ex1);
      }
    }
  }
  __syncthreads();

  // ---- E1: scalar-out MFMAs -> vout staging (x ex). vout aliases sw_v+ads:
  //      barrier between fragment loads and the overwrite.
  {
    bshort8 fa[6];
    #pragma unroll
    for (int kt=0;kt<6;kt++) fa[kt] = *(const bshort8*)&ads[l15*200 + kt*32 + quad*8];
    __syncthreads();   // all lanes' fa loads complete before vout overwrites ads
    #pragma unroll
    for (int t=0;t<2;t++) {
      int h = wave + 4*t;
      float bb = bval[h*16 + l15];
      floatx4 acc = {bb,bb,bb,bb};
      #pragma unroll
      for (int kt=0;kt<6;kt++)
        acc = MFMA16(fa[kt], *(const bshort8*)&swz[O_WVS + ((h*6+kt)*64+lane)*8], acc);
      #pragma unroll
      for (int r=0;r<4;r++) {
        int row = quad*4 + r;
        vout[row*132 + h*16 + l15] = acc[r]*s_ex[row*8+h];
      }
    }
  }
  __syncthreads();

  // ---- F1: 16-edge run-compressed scalar scatter
  if (tid < 128) {
    const int j = tid, h = j>>4, jj = j&15;
    float acc = 0.f; int cur = s_dst[0];
    #pragma unroll
    for (int e = 0; e < 16; ++e) {
      int d = s_dst[e];
      if (d != cur) { atomicAdd(&num[cur*320 + h*40 + jj], acc); acc = 0.f; cur = d; }
      acc += vout[e*132 + j];
    }
    atomicAdd(&num[cur*320 + h*40 + jj], acc);
  }
  __syncthreads();

  // ---- E2: vector MFMAs -> vout staging (x ex); writes stay in [0,12544)
  //      so at1/advb (live fragment sources) are untouched: no extra barrier
  {
    bshort8 ft[4];
    #pragma unroll
    for (int kt=0;kt<4;kt++) ft[kt] = *(const bshort8*)&at1[l15*136 + kt*32 + quad*8];
    floatx4 vsh = {0.f,0.f,0.f,0.f};
    #pragma unroll
    for (int kt=0;kt<4;kt++)
      vsh = MFMA16(ft[kt], *(const bshort8*)&swz[O_WVVT + ((wave*4+kt)*64+lane)*8], vsh);
    const int k = wave*16 + l15;
    const int h = k>>3, q = k&7;
    floatx4 vb0, vb1, vb2;
    { // hoist c-invariant WVVB fragments (used 3x)
      bshort8 wb[4];
      #pragma unroll
      for (int kt=0;kt<4;kt++) wb[kt] = *(const bshort8*)&swz[O_WVVB + ((wave*4+kt)*64+lane)*8];
      #pragma unroll
      for (int c=0;c<3;c++) {
        floatx4 acc = {0.f,0.f,0.f,0.f};
        #pragma unroll
        for (int kt=0;kt<4;kt++) {
          bshort8 fb = *(const bshort8*)&advb[c*2176 + l15*136 + kt*32 + quad*8];
          acc = MFMA16(fb, wb[kt], acc);
        }
        if (c==0) vb0 = acc; else if (c==1) vb1 = acc; else vb2 = acc;
      }
    }
    #pragma unroll
    for (int r=0;r<4;r++) {
      int row = quad*4 + r;
      float exr = s_ex[row*8+h];
      vout[row*194 + h*24 + q*3 + 0] = (vb0[r] + s_e1[0*16+row]*vsh[r])*exr;
      vout[row*194 + h*24 + q*3 + 1] = (vb1[r] + s_e1[1*16+row]*vsh[r])*exr;
      vout[row*194 + h*24 + q*3 + 2] = (vb2[r] + s_e1[2*16+row]*vsh[r])*exr;
    }
  }
  __syncthreads();

  // ---- F2: 16-edge run-compressed vector scatter
  if (tid < 192) {
    const int jj = tid;
    const int h = jj/24, rr = jj - h*24;
    float acc = 0.f; int cur = s_dst[0];
    #pragma unroll
    for (int e = 0; e < 16; ++e) {
      int d = s_dst[e];
      if (d != cur) { atomicAdd(&num[cur*320 + h*40 + 16 + rr], acc); acc = 0.f; cur = d; }
      acc += vout[e*194 + jj];
    }
    atomicAdd(&num[cur*320 + h*40 + 16 + rr], acc);
  }
}

// ---------------------------------------------------------------- node post (fp32 GEMV, 16 nodes/block)
__global__ __launch_bounds__(256) void node_post(
    const float* __restrict__ num, const float* __restrict__ den,
    const float* __restrict__ Wproj_s, const float* __restrict__ bproj,
    const float* __restrict__ Wproj_v, float* __restrict__ out) {
  __shared__ __align__(16) float s_ns[128*16];
  __shared__ __align__(16) float s_nv[192*16];
  const int tid = threadIdx.x;
  const int n0 = blockIdx.x*16;
  for (int idx = tid; idx < 16*320; idx += 256) {
    int n = idx/320, j = idx - n*320;
    int h = j/40, r = j - h*40;
    float a = num[(n0+n)*320+j] / (den[(n0+n)*8+h] + 1e-16f);
    if (r < 16) s_ns[(h*16+r)*16+n] = a;
    else        s_nv[(h*24 + (r-16))*16+n] = a;
  }
  __syncthreads();
  {
    int g = tid>>7, j = tid&127;
    float acc[8]; float b = bproj[j];
    #pragma unroll
    for (int i=0;i<8;i++) acc[i]=b;
    for (int k=0;k<128;k++) {
      float wv = Wproj_s[k*128+j];
      float4 a0 = *(const float4*)&s_ns[k*16+g*8];
      float4 a1 = *(const float4*)&s_ns[k*16+g*8+4];
      acc[0]+=a0.x*wv; acc[1]+=a0.y*wv; acc[2]+=a0.z*wv; acc[3]+=a0.w*wv;
      acc[4]+=a1.x*wv; acc[5]+=a1.y*wv; acc[6]+=a1.z*wv; acc[7]+=a1.w*wv;
    }
    #pragma unroll
    for (int i=0;i<8;i++) out[(n0+g*8+i)*320 + j] = acc[i];
  }
  if (tid < 192) {
    int c = tid>>6, k = tid&63;
    #pragma unroll
    for (int half=0; half<2; ++half) {
      float acc[8];
      #pragma unroll
      for (int e=0;e<8;e++) acc[e]=0.f;
      for (int m=0;m<64;m++) {
        float wv = Wproj_v[m*64+k];
        float4 v0 = *(const float4*)&s_nv[(m*3+c)*16 + half*8];
        float4 v1 = *(const float4*)&s_nv[(m*3+c)*16 + half*8 + 4];
        acc[0]+=v0.x*wv; acc[1]+=v0.y*wv; acc[2]+=v0.z*wv; acc[3]+=v0.w*wv;
        acc[4]+=v1.x*wv; acc[5]+=v1.y*wv; acc[6]+=v1.z*wv; acc[7]+=v1.w*wv;
      }
      #pragma unroll
      for (int e=0;e<8;e++) out[(n0+half*8+e)*320 + 128 + k*3 + c] = acc[e];
    }
  }
}

// ---------------------------------------------------------------- launch
extern "C" void kernel_launch(void* const* d_in, const int* in_sizes, int n_in,
                              void* d_out, int out_size, void* d_ws, size_t ws_size,
                              hipStream_t stream) {
  (void)in_sizes; (void)n_in; (void)out_size; (void)ws_size;
  const float* node_input = (const float*)d_in[0];
  const int*   esrc       = (const int*)d_in[1];
  const int*   edst       = (const int*)d_in[2];
  const float* eattr      = (const float*)d_in[3];
  const float* escal      = (const float*)d_in[4];
  const float* Wsrc_s     = (const float*)d_in[5];
  const float* Wsrc_v     = (const float*)d_in[6];
  const float* bsrc       = (const float*)d_in[7];
  const float* Wdst_s     = (const float*)d_in[8];
  const float* Wdst_v     = (const float*)d_in[9];
  const float* rad_W1     = (const float*)d_in[10];
  const float* rad_b1     = (const float*)d_in[11];
  const float* rad_W2     = (const float*)d_in[12];
  const float* rad_off    = (const float*)d_in[13];
  const float* Wact_s     = (const float*)d_in[14];
  const float* bact       = (const float*)d_in[15];
  const float* Wact_v     = (const float*)d_in[16];
  const float* Walpha     = (const float*)d_in[17];
  const float* balpha     = (const float*)d_in[18];
  const float* w_int      = (const float*)d_in[19];
  const float* Wval_s     = (const float*)d_in[20];
  const float* bval       = (const float*)d_in[21];
  const float* Wval_v     = (const float*)d_in[22];
  const float* alpha_dot  = (const float*)d_in[23];
  const float* Wproj_s    = (const float*)d_in[24];
  const float* bproj      = (const float*)d_in[25];
  const float* Wproj_v    = (const float*)d_in[26];
  float* out = (float*)d_out;

  char* wsb = (char*)d_ws;
  unsigned short* ms_s16 = (unsigned short*)(wsb);              //  2,560,000 B
  unsigned short* md_s16 = (unsigned short*)(wsb + 2560000);    //  2,560,000 B
  unsigned short* ms_v16 = (unsigned short*)(wsb + 5120000);    //  3,840,000 B (planar)
  unsigned short* md_v16 = (unsigned short*)(wsb + 8960000);    //  3,840,000 B
  float* den             = (float*)(wsb + 12800000);            //    320,000 B
  float* num             = (float*)(wsb + 13120000);            // 12,800,000 B
  unsigned short* swz    = (unsigned short*)(wsb + 25920000);   //    299,008 B
  int* cnt  = (int*)(wsb + 26220032);                           //     40,000 B
  int* rank = (int*)(wsb + 26260032);                           //     40,000 B
  int* perm = (int*)(wsb + 26300032);                           //    640,000 B -> ~26.9 MB

  k_pre_all<<<3375, 256, 0, stream>>>(node_input, Wsrc_s, Wsrc_v, bsrc, Wdst_s, Wdst_v,
                                      ms_s16, md_s16, ms_v16, md_v16,
                                      rad_W1, rad_W2, Wact_s, Wact_v, Wval_s, Wval_v,
                                      Walpha, w_int, swz, num, den, cnt, rank);
  k_hist<<<625, 256, 0, stream>>>(edst, cnt);
  k_scan_scatter<<<625, 256, 0, stream>>>(cnt, rank, edst, perm);
  e_all<<<10000, 256, 0, stream>>>(ms_s16, md_s16, ms_v16, md_v16, esrc, edst, perm, eattr, escal,
                                   rad_b1, rad_off, bact, bval,
                                   balpha, alpha_dot, swz, den, num);
  node_post<<<625, 256, 0, stream>>>(num, den, Wproj_s, bproj, Wproj_v, out);
}

// Round 9
// 375.062 us; speedup vs baseline: 1.1815x; 1.0020x over previous
//
#include <hip/hip_runtime.h>

#define NN 10000
#define NE 160000
#define INV_SQRT3f 0.57735026918962576f
#define INV_SQRT2f 0.70710678118654752f
#define VPLU 640000   // vector plane length (NN*64 ushorts)

typedef short bshort8 __attribute__((ext_vector_type(8)));
typedef float floatx4 __attribute__((ext_vector_type(4)));
#define MFMA16(a,b,c) __builtin_amdgcn_mfma_f32_16x16x32_bf16((a),(b),(c),0,0,0)

__device__ __forceinline__ float sigm(float x){ return 1.f/(1.f+__expf(-x)); }
__device__ __forceinline__ float siluf(float x){ return x*sigm(x); }
__device__ __forceinline__ float sleaky(float x){ return 0.6f*x + 0.4f*x*(2.f*sigm(x)-1.f); }
// round-half-up bf16 convert: 2 VALU ops vs 5 for RNE
__device__ __forceinline__ unsigned short f2bf(float f){
  return (unsigned short)((__float_as_uint(f) + 0x8000u)>>16);
}
__device__ __forceinline__ float bf2f(unsigned short h){
  return __uint_as_float(((unsigned)h)<<16);
}
// packed 2xbf16 convert (RNE), 1 VALU op for 2 values
__device__ __forceinline__ unsigned cvtpk(float lo, float hi){
  unsigned r;
  asm("v_cvt_pk_bf16_f32 %0, %1, %2" : "=v"(r) : "v"(lo), "v"(hi));
  return r;
}
// unpack 2xbf16 from a dword: 1 VALU op each
__device__ __forceinline__ float lo16f(unsigned u){ return __uint_as_float(u<<16); }
__device__ __forceinline__ float hi16f(unsigned u){ return __uint_as_float(u & 0xffff0000u); }

// swizzled-weight segment offsets (in ushorts)
#define O_W1   0
#define O_W2   2048
#define O_WAS  30720
#define O_WAVT 67584
#define O_WAVB 75776
#define O_WVS  83968
#define O_WVVT 108544
#define O_WVVB 116736
#define O_WALP 124928
#define SWZ_TOTAL 149504

// ---------------------------------------------------------------- merged pre-pass:
//  blocks [0,625): node_pre, 16 nodes/block (fp32 GEMV -> bf16 planar staging)
//  blocks [625,1209): weight pre-swizzle (w_int/INV_SQRT* folded into dtp2 weights)
//  blocks [1209,1834): edge histogram (cnt zeroed by preceding hipMemsetAsync)
//  blocks [1834,4000): grid-stride zero of num/den
__global__ __launch_bounds__(256) void k_pre_all(
    const float* __restrict__ x,
    const float* __restrict__ Wsrc_s, const float* __restrict__ Wsrc_v,
    const float* __restrict__ bsrc,
    const float* __restrict__ Wdst_s, const float* __restrict__ Wdst_v,
    unsigned short* __restrict__ ms_s, unsigned short* __restrict__ md_s,
    unsigned short* __restrict__ ms_v, unsigned short* __restrict__ md_v,
    const float* __restrict__ W1, const float* __restrict__ W2,
    const float* __restrict__ WAs, const float* __restrict__ WAv,
    const float* __restrict__ WVs, const float* __restrict__ WVv,
    const float* __restrict__ WAl, const float* __restrict__ w_int,
    unsigned short* __restrict__ swz,
    const int* __restrict__ edst, int* __restrict__ cnt,
    float* __restrict__ num, float* __restrict__ den) {
  __shared__ __align__(16) float s_s[128*16];
  __shared__ __align__(16) float s_v[192*16];
  const int tid = threadIdx.x;
  const int b = blockIdx.x;
  if (b >= 1834) {            // ---- init branch (num/den only; cnt/rank via memset)
    int base = (b-1834)*256 + tid;      // [0, 554496)
    float4 z = {0.f,0.f,0.f,0.f};
    for (int i = base; i < 800000; i += 554496) ((float4*)num)[i] = z;
    if (base < 20000) ((float4*)den)[base] = z;
    return;
  }
  if (b >= 1209) {            // ---- histogram branch
    int e = (b-1209)*256 + tid;
    if (e < NE) atomicAdd(&cnt[edst[e]], 1);
    return;
  }
  if (b >= 625) {             // ---- weight swizzle branch
    int s = (b-625)*256 + tid;
    if (s >= SWZ_TOTAL) return;
    const float* src; int base, N, KT, rowOff;
    if      (s < 2048)  { base=O_W1;   src=W1;  N=64;  KT=1; rowOff=0; }
    else if (s < 30720) { base=O_W2;   src=W2;  N=448; KT=2; rowOff=0; }
    else if (s < 67584) { base=O_WAS;  src=WAs; N=192; KT=6; rowOff=0; }
    else if (s < 75776) { base=O_WAVT; src=WAv; N=64;  KT=4; rowOff=0; }
    else if (s < 83968) { base=O_WAVB; src=WAv; N=64;  KT=4; rowOff=128; }
    else if (s < 108544){ base=O_WVS;  src=WVs; N=128; KT=6; rowOff=0; }
    else if (s < 116736){ base=O_WVVT; src=WVv; N=64;  KT=4; rowOff=0; }
    else if (s < 124928){ base=O_WVVB; src=WVv; N=64;  KT=4; rowOff=128; }
    else                { base=O_WALP; src=WAl; N=128; KT=6; rowOff=0; }
    int loc = s - base;
    int j = loc & 7, l = (loc>>3)&63, kt = (loc>>9)%KT, nt = loc/(512*KT);
    int row = kt*32 + (l>>4)*8 + j + rowOff;
    int col = nt*16 + (l&15);
    // fold w_int (and the dtp2 INV_SQRT* constants) into the dtp2 weights
    float scl = 1.f;
    if      (base == O_WVS)  scl = (row < 128) ? w_int[row] : w_int[192+row]*INV_SQRT3f;
    else if (base == O_WVVT) scl = w_int[128+row];
    else if (base == O_WVVB) scl = (row < 192) ? w_int[128+row] : w_int[192+row]*INV_SQRT2f;
    swz[s] = f2bf(src[row*N + col] * scl);
    return;
  }
  // ---- node_pre branch: 16 nodes per block, planar vector staging
  const int n0 = b*16;
  for (int idx = tid; idx < 16*320; idx += 256) {
    int n = idx/320, d = idx - n*320;
    float val = x[(n0+n)*320 + d];
    if (d < 128) s_s[d*16+n] = val;
    else         s_v[(d-128)*16+n] = val;
  }
  __syncthreads();
  {
    int g = tid>>7, j = tid&127;    // g selects nodes g*8..g*8+7
    float accs[8], accd[8];
    float bb = bsrc[j];
    #pragma unroll
    for (int i=0;i<8;i++){ accs[i]=bb; accd[i]=0.f; }
    for (int k=0;k<128;k++) {
      float w1 = Wsrc_s[k*128+j], w2 = Wdst_s[k*128+j];
      float4 a0 = *(const float4*)&s_s[k*16+g*8];
      float4 a1 = *(const float4*)&s_s[k*16+g*8+4];
      accs[0]+=a0.x*w1; accs[1]+=a0.y*w1; accs[2]+=a0.z*w1; accs[3]+=a0.w*w1;
      accs[4]+=a1.x*w1; accs[5]+=a1.y*w1; accs[6]+=a1.z*w1; accs[7]+=a1.w*w1;
      accd[0]+=a0.x*w2; accd[1]+=a0.y*w2; accd[2]+=a0.z*w2; accd[3]+=a0.w*w2;
      accd[4]+=a1.x*w2; accd[5]+=a1.y*w2; accd[6]+=a1.z*w2; accd[7]+=a1.w*w2;
    }
    #pragma unroll
    for (int i=0;i<8;i++){ int n=n0+g*8+i; ms_s[n*128+j]=f2bf(accs[i]); md_s[n*128+j]=f2bf(accd[i]); }
  }
  if (tid < 192) {
    int c = tid>>6, k = tid&63;
    #pragma unroll
    for (int half=0; half<2; ++half) {
      float accs[8], accd[8];
      #pragma unroll
      for (int e=0;e<8;e++){ accs[e]=0.f; accd[e]=0.f; }
      for (int m=0;m<64;m++) {
        float w1 = Wsrc_v[m*64+k], w2 = Wdst_v[m*64+k];
        float4 v0 = *(const float4*)&s_v[(m*3+c)*16 + half*8];
        float4 v1 = *(const float4*)&s_v[(m*3+c)*16 + half*8 + 4];
        accs[0]+=v0.x*w1; accs[1]+=v0.y*w1; accs[2]+=v0.z*w1; accs[3]+=v0.w*w1;
        accs[4]+=v1.x*w1; accs[5]+=v1.y*w1; accs[6]+=v1.z*w1; accs[7]+=v1.w*w1;
        accd[0]+=v0.x*w2; accd[1]+=v0.y*w2; accd[2]+=v0.z*w2; accd[3]+=v0.w*w2;
        accd[4]+=v1.x*w2; accd[5]+=v1.y*w2; accd[6]+=v1.z*w2; accd[7]+=v1.w*w2;
      }
      #pragma unroll
      for (int e=0;e<8;e++){
        int n = n0 + half*8 + e;
        ms_v[c*VPLU + n*64 + k] = f2bf(accs[e]);
        md_v[c*VPLU + n*64 + k] = f2bf(accd[e]);
      }
    }
  }
}

// merged scan+scatter: every block redundantly computes the full exclusive scan
// of cnt in LDS (parallel across CUs, no cross-block dependency), then scatters
// its 256 edges at pos = scan[dst] + global-atomic-rank[dst].
__global__ __launch_bounds__(256) void k_scan_scatter(
    const int* __restrict__ cnt, int* __restrict__ rank,
    const int* __restrict__ edst, int* __restrict__ perm) {
  __shared__ int sc[10240];
  __shared__ int wsum[4];
  const int tid = threadIdx.x;
  const int lane = tid & 63, wave = tid >> 6;
  for (int i = tid; i < 10240; i += 256) sc[i] = (i < NN) ? cnt[i] : 0;
  __syncthreads();
  int v[40]; int s = 0;
  #pragma unroll
  for (int j=0;j<40;j++){ v[j] = sc[tid*40+j]; s += v[j]; }
  int incl = s;
  #pragma unroll
  for (int d=1; d<64; d<<=1) { int t = __shfl_up(incl, d, 64); if (lane>=d) incl += t; }
  if (lane==63) wsum[wave] = incl;
  __syncthreads();
  int wbase = 0;
  for (int w=0; w<wave; ++w) wbase += wsum[w];
  int excl = wbase + incl - s;
  // each thread owns sc[tid*40 .. tid*40+39]: safe to overwrite its own slice
  #pragma unroll
  for (int j=0;j<40;j++){ sc[tid*40+j] = excl; excl += v[j]; }
  __syncthreads();
  int e = blockIdx.x*256 + tid;
  if (e < NE) {
    int d = edst[e];
    int r = atomicAdd(&rank[d], 1);
    perm[sc[d] + r] = e;
  }
}

// ---------------------------------------------------------------- fused edge pass
// EXACT r7 structure (validated: 193us, FETCH 71MB, WRITE 45MB, conflicts 1.11e7).
// r8's k-quad B-vector reverted: its uint2 (8B/lane) LDS reads were a >=4-way
// bank conflict (64 lanes x 2 banks vs 32 banks); r7's b32 reads are the free
// 2-way case. [measured: r8 conflicts 1.11e7 -> 1.23e7, dur 193 -> 198]
__global__ __launch_bounds__(256, 5) void e_all(
    const unsigned short* __restrict__ ms_s, const unsigned short* __restrict__ md_s,
    const unsigned short* __restrict__ ms_v, const unsigned short* __restrict__ md_v,
    const int* __restrict__ esrc, const int* __restrict__ edst,
    const int* __restrict__ perm,
    const float* __restrict__ eattr, const float* __restrict__ escal,
    const float* __restrict__ rad_b1, const float* __restrict__ rad_off,
    const float* __restrict__ bact,
    const float* __restrict__ bval,
    const float* __restrict__ balpha, const float* __restrict__ alpha_dot,
    const unsigned short* __restrict__ swz,
    float* __restrict__ den, float* __restrict__ num) {
  __shared__ __align__(16) char smem[30912];
  unsigned short* sw_v = (unsigned short*)smem;            // 16x192 (w3|w4|w5) [0,6144)
  float* vout          = (float*)smem;                     // E1: 16x132, E2: 16x194 f32 [0,12544)
  unsigned short* ads  = (unsigned short*)(smem+6144);     // 16x200 (ds / vs) [6144,12544)
  unsigned short* at1  = (unsigned short*)(smem+12544);    // 16x136 (t1 / t2)
  unsigned short* advb = (unsigned short*)(smem+16896);    // 3x16x136 (dvB / vvB)
  unsigned short* aes  = (unsigned short*)(smem+16896);    // alias (dead pre-B)
  unsigned short* ah   = (unsigned short*)(smem+19456);    // alias (dead pre-B)
  float* s_e0 = (float*)(smem+29952);
  float* s_e1 = (float*)(smem+30016);
  float* s_ex = (float*)(smem+30208);
  int* s_eid  = (int*)(smem+30720);
  int* s_src  = (int*)(smem+30784);
  int* s_dst  = (int*)(smem+30848);
  const int tid  = threadIdx.x;
  const int lane = tid & 63, wave = tid >> 6;
  const int quad = lane >> 4, l15 = lane & 15;
  // bijective XCD-chunk swizzle (10000 = 8*1250)
  const int bswz = (blockIdx.x & 7)*1250 + (blockIdx.x >> 3);
  const int eb = bswz*16;

  if (tid < 16) {
    int eid = perm[eb+tid];
    s_eid[tid] = eid; s_src[tid] = esrc[eid]; s_dst[tid] = edst[eid];
  }
  __syncthreads();
  if (tid >= 64 && tid < 128) {
    int t = tid-64, e = t>>2, q = t&3;
    float a = eattr[s_eid[e]*4+q];
    if (q == 0) s_e0[e] = a; else s_e1[(q-1)*16+e] = a;
  }
  { // packed escal staging: 256 threads x 2 values
    int e = tid>>4, i0 = (tid&15)*2;
    float2 es = *(const float2*)&escal[s_eid[e]*32+i0];
    *(unsigned*)&aes[e*40+i0] = cvtpk(es.x, es.y);
  }
  __syncthreads();

  // ---- A1: h = silu(escal@W1+b1)
  {
    int nt = wave, col = nt*16 + l15;
    bshort8 a = *(const bshort8*)&aes[l15*40 + quad*8];
    bshort8 b = *(const bshort8*)&swz[O_W1 + (nt*64 + lane)*8];
    float bb = rad_b1[col];
    floatx4 acc = {bb,bb,bb,bb};
    acc = MFMA16(a, b, acc);
    #pragma unroll
    for (int r=0;r<4;r++) ah[(quad*4+r)*72 + col] = f2bf(siluf(acc[r]));
  }
  __syncthreads();

  // ---- A2': w tiles + fused B-scalar.
  //   w1/w2 (cols 0..255): lane holds w1[e][m] and w2[e][m] for the SAME (e,m)
  //   by pairing tiles nt and nt+8 -> one msgs gather feeds ads and at1.
  //   w3/w4/w5 (cols 256..447): store bf16 w to sw_v for the B-vector stage.
  {
    bshort8 ha0 = *(const bshort8*)&ah[l15*72 + quad*8];
    bshort8 ha1 = *(const bshort8*)&ah[l15*72 + 32 + quad*8];
    int src_[4], dst_[4];
    #pragma unroll
    for (int r=0;r<4;r++){ int e=quad*4+r; src_[r]=s_src[e]; dst_[r]=s_dst[e]; }
    #pragma unroll
    for (int p=0;p<2;p++) {
      int nt1 = wave*2+p, nt2 = nt1+8;
      int m = nt1*16 + l15;
      float o1 = rad_off[m], o2 = rad_off[128+m];
      floatx4 a1 = {o1,o1,o1,o1}, a2 = {o2,o2,o2,o2};
      a1 = MFMA16(ha0, *(const bshort8*)&swz[O_W2 + ((nt1*2+0)*64+lane)*8], a1);
      a1 = MFMA16(ha1, *(const bshort8*)&swz[O_W2 + ((nt1*2+1)*64+lane)*8], a1);
      a2 = MFMA16(ha0, *(const bshort8*)&swz[O_W2 + ((nt2*2+0)*64+lane)*8], a2);
      a2 = MFMA16(ha1, *(const bshort8*)&swz[O_W2 + ((nt2*2+1)*64+lane)*8], a2);
      #pragma unroll
      for (int r=0;r<4;r++) {
        int e = quad*4+r;
        float msgs = bf2f(ms_s[src_[r]*128+m]) + bf2f(md_s[dst_[r]*128+m]);
        ads[e*200+m] = f2bf(a1[r]*msgs*s_e0[e]);
        at1[e*136+m] = f2bf(a2[r]*msgs);
      }
    }
    #pragma unroll
    for (int q=0;q<3;q++) {
      int nt = 16 + wave*3 + q, col = nt*16 + l15;
      float o = rad_off[col];
      floatx4 acc = {o,o,o,o};
      acc = MFMA16(ha0, *(const bshort8*)&swz[O_W2 + ((nt*2+0)*64+lane)*8], acc);
      acc = MFMA16(ha1, *(const bshort8*)&swz[O_W2 + ((nt*2+1)*64+lane)*8], acc);
      #pragma unroll
      for (int r=0;r<4;r++) sw_v[(quad*4+r)*192 + (col-256)] = f2bf(acc[r]);
    }
  }
  __syncthreads();

  // ---- B-vector: dtp1 vector part, k-pairs (packed bf16x2 loads + cvt_pk writes)
  //      32 lanes/edge, 128B contiguous segments per plane, each row read once.
  #pragma unroll
  for (int it = 0; it < 2; ++it) {
    int t = tid + it*256;            // 0..511
    int e = t>>5, pr = t&31;
    int k0 = pr*2;
    int sb = s_src[e]*64 + k0, db = s_dst[e]*64 + k0;
    unsigned usx = *(const unsigned*)&ms_v[0*VPLU+sb];
    unsigned usy = *(const unsigned*)&ms_v[1*VPLU+sb];
    unsigned usz = *(const unsigned*)&ms_v[2*VPLU+sb];
    unsigned udx = *(const unsigned*)&md_v[0*VPLU+db];
    unsigned udy = *(const unsigned*)&md_v[1*VPLU+db];
    unsigned udz = *(const unsigned*)&md_v[2*VPLU+db];
    unsigned uw3 = *(const unsigned*)&sw_v[e*192 + k0];
    unsigned uw4 = *(const unsigned*)&sw_v[e*192 + 64 + k0];
    unsigned uw5 = *(const unsigned*)&sw_v[e*192 + 128 + k0];
    float ex1 = s_e1[0+e], ey1 = s_e1[16+e], ez1 = s_e1[32+e];
    float e0 = s_e0[e];
    float vx0 = lo16f(usx)+lo16f(udx), vx1 = hi16f(usx)+hi16f(udx);
    float vy0 = lo16f(usy)+lo16f(udy), vy1 = hi16f(usy)+hi16f(udy);
    float vz0 = lo16f(usz)+lo16f(udz), vz1 = hi16f(usz)+hi16f(udz);
    float d0 = vx0*ex1 + vy0*ey1 + vz0*ez1;
    float d1 = vx1*ex1 + vy1*ey1 + vz1*ez1;
    *(unsigned*)&ads[e*200+128+k0] =
        cvtpk(lo16f(uw4)*d0*INV_SQRT3f, hi16f(uw4)*d1*INV_SQRT3f);
    float w30 = lo16f(uw3)*e0, w31 = hi16f(uw3)*e0;
    float w50 = lo16f(uw5)*INV_SQRT2f, w51 = hi16f(uw5)*INV_SQRT2f;
    *(unsigned*)&advb[0*2176 + e*136 + k0] = cvtpk(w30*vx0, w31*vx1);
    *(unsigned*)&advb[1*2176 + e*136 + k0] = cvtpk(w30*vy0, w31*vy1);
    *(unsigned*)&advb[2*2176 + e*136 + k0] = cvtpk(w30*vz0, w31*vz1);
    *(unsigned*)&advb[0*2176 + e*136 + 64+k0] =
        cvtpk(w50*(vy0*ez1 - vz0*ey1), w51*(vy1*ez1 - vz1*ey1));
    *(unsigned*)&advb[1*2176 + e*136 + 64+k0] =
        cvtpk(w50*(vz0*ex1 - vx0*ez1), w51*(vz1*ex1 - vx1*ez1));
    *(unsigned*)&advb[2*2176 + e*136 + 64+k0] =
        cvtpk(w50*(vx0*ey1 - vy0*ex1), w51*(vx1*ey1 - vy1*ex1));
  }
  __syncthreads();

  // ---- CD (fused): all MFMAs with fragments in regs, then activations + dtp2 writes
  floatx4 sc0, sc1, sc2, gsa, gb0, gb1, gb2;
  {
    bshort8 fa[6];
    #pragma unroll
    for (int kt=0;kt<6;kt++) fa[kt] = *(const bshort8*)&ads[l15*200 + kt*32 + quad*8];
    // alpha logits + ex/den (run-compressed den atomics over 4 sorted edges)
    #pragma unroll
    for (int t=0;t<2;t++) {
      int h = wave*2 + t;
      int col = h*16 + l15;
      float bb = balpha[col];
      floatx4 acc = {bb,bb,bb,bb};
      #pragma unroll
      for (int kt=0;kt<6;kt++)
        acc = MFMA16(fa[kt], *(const bshort8*)&swz[O_WALP + ((h*6+kt)*64+lane)*8], acc);
      float ad = alpha_dot[col];
      float exv[4];
      #pragma unroll
      for (int r=0;r<4;r++) {
        float p = sleaky(acc[r])*ad;
        p += __shfl_xor(p, 1);
        p += __shfl_xor(p, 2);
        p += __shfl_xor(p, 4);
        p += __shfl_xor(p, 8);
        float ex = __expf(p);
        exv[r] = ex;
        if (l15 == 0) s_ex[(quad*4+r)*8+h] = ex;
      }
      if (l15 == 0) {
        float racc = exv[0]; int cur = s_dst[quad*4];
        #pragma unroll
        for (int r=1;r<4;r++) {
          int d = s_dst[quad*4+r];
          if (d != cur) { atomicAdd(&den[cur*8+h], racc); racc = 0.f; cur = d; }
          racc += exv[r];
        }
        atomicAdd(&den[cur*8+h], racc);
      }
    }
    // scal tiles
    {
      float bb = bact[wave*16 + l15];
      floatx4 a0 = {bb,bb,bb,bb};
      #pragma unroll
      for (int kt=0;kt<6;kt++)
        a0 = MFMA16(fa[kt], *(const bshort8*)&swz[O_WAS + ((wave*6+kt)*64+lane)*8], a0);
      sc0 = a0;
    }
    {
      float bb = bact[(wave+4)*16 + l15];
      floatx4 a1 = {bb,bb,bb,bb};
      #pragma unroll
      for (int kt=0;kt<6;kt++)
        a1 = MFMA16(fa[kt], *(const bshort8*)&swz[O_WAS + (((wave+4)*6+kt)*64+lane)*8], a1);
      sc1 = a1;
    }
    {
      float bb = bact[(wave+8)*16 + l15];
      floatx4 a2 = {bb,bb,bb,bb};
      #pragma unroll
      for (int kt=0;kt<6;kt++)
        a2 = MFMA16(fa[kt], *(const bshort8*)&swz[O_WAS + (((wave+8)*6+kt)*64+lane)*8], a2);
      sc2 = a2;
    }
    bshort8 ft[4];
    #pragma unroll
    for (int kt=0;kt<4;kt++) ft[kt] = *(const bshort8*)&at1[l15*136 + kt*32 + quad*8];
    {
      floatx4 acc = {0.f,0.f,0.f,0.f};
      #pragma unroll
      for (int kt=0;kt<4;kt++)
        acc = MFMA16(ft[kt], *(const bshort8*)&swz[O_WAVT + ((wave*4+kt)*64+lane)*8], acc);
      gsa = acc;
    }
    { // hoist c-invariant WAVB fragments (used 3x)
      bshort8 wb[4];
      #pragma unroll
      for (int kt=0;kt<4;kt++) wb[kt] = *(const bshort8*)&swz[O_WAVB + ((wave*4+kt)*64+lane)*8];
      #pragma unroll
      for (int c=0;c<3;c++) {
        floatx4 acc = {0.f,0.f,0.f,0.f};
        #pragma unroll
        for (int kt=0;kt<4;kt++) {
          bshort8 fb = *(const bshort8*)&advb[c*2176 + l15*136 + kt*32 + quad*8];
          acc = MFMA16(fb, wb[kt], acc);
        }
        if (c==0) gb0 = acc; else if (c==1) gb1 = acc; else gb2 = acc;
      }
    }
  }
  __syncthreads();   // all fragment reads done; safe to overwrite ads/at1/advb

  // ---- CDw: activations + dtp2 writes (w_int pre-folded into dtp2 weights)
  {
    const int k = wave*16 + l15;       // 0..63
    #pragma unroll
    for (int r=0;r<4;r++) {
      int row = quad*4 + r;
      float e0 = s_e0[row];
      { // silu path, tile t0: m = k
        float v = siluf(sc0[r]);
        ads[row*200+k] = f2bf(v*e0);
        at1[row*136+k] = f2bf(v);
      }
      { // silu path, tile t1: m = 64+k
        float v = siluf(sc1[r]);
        ads[row*200+64+k] = f2bf(v*e0);
        at1[row*136+64+k] = f2bf(v);
      }
      { // gated vector path (tile t2 gives scal[128+k])
        float sg = sigm(sc2[r]);
        float gs = gsa[r];
        float ex1 = s_e1[0+row], ey1 = s_e1[16+row], ez1 = s_e1[32+row];
        float v0 = (gs*ex1 + gb0[r])*sg;
        float v1 = (gs*ey1 + gb1[r])*sg;
        float v2 = (gs*ez1 + gb2[r])*sg;
        float d = v0*ex1 + v1*ey1 + v2*ez1;
        ads[row*200+128+k] = f2bf(d);
        advb[0*2176 + row*136 + k] = f2bf(v0*e0);
        advb[1*2176 + row*136 + k] = f2bf(v1*e0);
        advb[2*2176 + row*136 + k] = f2bf(v2*e0);
        advb[0*2176 + row*136 + 64+k] = f2bf(v1*ez1 - v2*ey1);
        advb[1*2176 + row*136 + 64+k] = f2bf(v2*ex1 - v0*ez1);
        advb[2*2176 + row*136 + 64+k] = f2bf(v0*ey1 - v1*ex1);
      }
    }
  }
  __syncthreads();

  // ---- E1: scalar-out MFMAs -> vout staging (x ex). vout aliases sw_v+ads:
  //      barrier between fragment loads and the overwrite.
  {
    bshort8 fa[6];
    #pragma unroll
    for (int kt=0;kt<6;kt++) fa[kt] = *(const bshort8*)&ads[l15*200 + kt*32 + quad*8];
    __syncthreads();   // all lanes' fa loads complete before vout overwrites ads
    #pragma unroll
    for (int t=0;t<2;t++) {
      int h = wave + 4*t;
      float bb = bval[h*16 + l15];
      floatx4 acc = {bb,bb,bb,bb};
      #pragma unroll
      for (int kt=0;kt<6;kt++)
        acc = MFMA16(fa[kt], *(const bshort8*)&swz[O_WVS + ((h*6+kt)*64+lane)*8], acc);
      #pragma unroll
      for (int r=0;r<4;r++) {
        int row = quad*4 + r;
        vout[row*132 + h*16 + l15] = acc[r]*s_ex[row*8+h];
      }
    }
  }
  __syncthreads();

  // ---- F1: 16-edge run-compressed scalar scatter
  if (tid < 128) {
    const int j = tid, h = j>>4, jj = j&15;
    float acc = 0.f; int cur = s_dst[0];
    #pragma unroll
    for (int e = 0; e < 16; ++e) {
      int d = s_dst[e];
      if (d != cur) { atomicAdd(&num[cur*320 + h*40 + jj], acc); acc = 0.f; cur = d; }
      acc += vout[e*132 + j];
    }
    atomicAdd(&num[cur*320 + h*40 + jj], acc);
  }
  __syncthreads();

  // ---- E2: vector MFMAs -> vout staging (x ex); writes stay in [0,12544)
  //      so at1/advb (live fragment sources) are untouched: no extra barrier
  {
    bshort8 ft[4];
    #pragma unroll
    for (int kt=0;kt<4;kt++) ft[kt] = *(const bshort8*)&at1[l15*136 + kt*32 + quad*8];
    floatx4 vsh = {0.f,0.f,0.f,0.f};
    #pragma unroll
    for (int kt=0;kt<4;kt++)
      vsh = MFMA16(ft[kt], *(const bshort8*)&swz[O_WVVT + ((wave*4+kt)*64+lane)*8], vsh);
    const int k = wave*16 + l15;
    const int h = k>>3, q = k&7;
    floatx4 vb0, vb1, vb2;
    { // hoist c-invariant WVVB fragments (used 3x)
      bshort8 wb[4];
      #pragma unroll
      for (int kt=0;kt<4;kt++) wb[kt] = *(const bshort8*)&swz[O_WVVB + ((wave*4+kt)*64+lane)*8];
      #pragma unroll
      for (int c=0;c<3;c++) {
        floatx4 acc = {0.f,0.f,0.f,0.f};
        #pragma unroll
        for (int kt=0;kt<4;kt++) {
          bshort8 fb = *(const bshort8*)&advb[c*2176 + l15*136 + kt*32 + quad*8];
          acc = MFMA16(fb, wb[kt], acc);
        }
        if (c==0) vb0 = acc; else if (c==1) vb1 = acc; else vb2 = acc;
      }
    }
    #pragma unroll
    for (int r=0;r<4;r++) {
      int row = quad*4 + r;
      float exr = s_ex[row*8+h];
      vout[row*194 + h*24 + q*3 + 0] = (vb0[r] + s_e1[0*16+row]*vsh[r])*exr;
      vout[row*194 + h*24 + q*3 + 1] = (vb1[r] + s_e1[1*16+row]*vsh[r])*exr;
      vout[row*194 + h*24 + q*3 + 2] = (vb2[r] + s_e1[2*16+row]*vsh[r])*exr;
    }
  }
  __syncthreads();

  // ---- F2: 16-edge run-compressed vector scatter
  if (tid < 192) {
    const int jj = tid;
    const int h = jj/24, rr = jj - h*24;
    float acc = 0.f; int cur = s_dst[0];
    #pragma unroll
    for (int e = 0; e < 16; ++e) {
      int d = s_dst[e];
      if (d != cur) { atomicAdd(&num[cur*320 + h*40 + 16 + rr], acc); acc = 0.f; cur = d; }
      acc += vout[e*194 + jj];
    }
    atomicAdd(&num[cur*320 + h*40 + 16 + rr], acc);
  }
}

// ---------------------------------------------------------------- node post (fp32 GEMV, 16 nodes/block)
__global__ __launch_bounds__(256) void node_post(
    const float* __restrict__ num, const float* __restrict__ den,
    const float* __restrict__ Wproj_s, const float* __restrict__ bproj,
    const float* __restrict__ Wproj_v, float* __restrict__ out) {
  __shared__ __align__(16) float s_ns[128*16];
  __shared__ __align__(16) float s_nv[192*16];
  const int tid = threadIdx.x;
  const int n0 = blockIdx.x*16;
  for (int idx = tid; idx < 16*320; idx += 256) {
    int n = idx/320, j = idx - n*320;
    int h = j/40, r = j - h*40;
    float a = num[(n0+n)*320+j] / (den[(n0+n)*8+h] + 1e-16f);
    if (r < 16) s_ns[(h*16+r)*16+n] = a;
    else        s_nv[(h*24 + (r-16))*16+n] = a;
  }
  __syncthreads();
  {
    int g = tid>>7, j = tid&127;
    float acc[8]; float b = bproj[j];
    #pragma unroll
    for (int i=0;i<8;i++) acc[i]=b;
    for (int k=0;k<128;k++) {
      float wv = Wproj_s[k*128+j];
      float4 a0 = *(const float4*)&s_ns[k*16+g*8];
      float4 a1 = *(const float4*)&s_ns[k*16+g*8+4];
      acc[0]+=a0.x*wv; acc[1]+=a0.y*wv; acc[2]+=a0.z*wv; acc[3]+=a0.w*wv;
      acc[4]+=a1.x*wv; acc[5]+=a1.y*wv; acc[6]+=a1.z*wv; acc[7]+=a1.w*wv;
    }
    #pragma unroll
    for (int i=0;i<8;i++) out[(n0+g*8+i)*320 + j] = acc[i];
  }
  if (tid < 192) {
    int c = tid>>6, k = tid&63;
    #pragma unroll
    for (int half=0; half<2; ++half) {
      float acc[8];
      #pragma unroll
      for (int e=0;e<8;e++) acc[e]=0.f;
      for (int m=0;m<64;m++) {
        float wv = Wproj_v[m*64+k];
        float4 v0 = *(const float4*)&s_nv[(m*3+c)*16 + half*8];
        float4 v1 = *(const float4*)&s_nv[(m*3+c)*16 + half*8 + 4];
        acc[0]+=v0.x*wv; acc[1]+=v0.y*wv; acc[2]+=v0.z*wv; acc[3]+=v0.w*wv;
        acc[4]+=v1.x*wv; acc[5]+=v1.y*wv; acc[6]+=v1.z*wv; acc[7]+=v1.w*wv;
      }
      #pragma unroll
      for (int e=0;e<8;e++) out[(n0+half*8+e)*320 + 128 + k*3 + c] = acc[e];
    }
  }
}

// ---------------------------------------------------------------- launch
extern "C" void kernel_launch(void* const* d_in, const int* in_sizes, int n_in,
                              void* d_out, int out_size, void* d_ws, size_t ws_size,
                              hipStream_t stream) {
  (void)in_sizes; (void)n_in; (void)out_size; (void)ws_size;
  const float* node_input = (const float*)d_in[0];
  const int*   esrc       = (const int*)d_in[1];
  const int*   edst       = (const int*)d_in[2];
  const float* eattr      = (const float*)d_in[3];
  const float* escal      = (const float*)d_in[4];
  const float* Wsrc_s     = (const float*)d_in[5];
  const float* Wsrc_v     = (const float*)d_in[6];
  const float* bsrc       = (const float*)d_in[7];
  const float* Wdst_s     = (const float*)d_in[8];
  const float* Wdst_v     = (const float*)d_in[9];
  const float* rad_W1     = (const float*)d_in[10];
  const float* rad_b1     = (const float*)d_in[11];
  const float* rad_W2     = (const float*)d_in[12];
  const float* rad_off    = (const float*)d_in[13];
  const float* Wact_s     = (const float*)d_in[14];
  const float* bact       = (const float*)d_in[15];
  const float* Wact_v     = (const float*)d_in[16];
  const float* Walpha     = (const float*)d_in[17];
  const float* balpha     = (const float*)d_in[18];
  const float* w_int      = (const float*)d_in[19];
  const float* Wval_s     = (const float*)d_in[20];
  const float* bval       = (const float*)d_in[21];
  const float* Wval_v     = (const float*)d_in[22];
  const float* alpha_dot  = (const float*)d_in[23];
  const float* Wproj_s    = (const float*)d_in[24];
  const float* bproj      = (const float*)d_in[25];
  const float* Wproj_v    = (const float*)d_in[26];
  float* out = (float*)d_out;

  char* wsb = (char*)d_ws;
  unsigned short* ms_s16 = (unsigned short*)(wsb);              //  2,560,000 B
  unsigned short* md_s16 = (unsigned short*)(wsb + 2560000);    //  2,560,000 B
  unsigned short* ms_v16 = (unsigned short*)(wsb + 5120000);    //  3,840,000 B (planar)
  unsigned short* md_v16 = (unsigned short*)(wsb + 8960000);    //  3,840,000 B
  float* den             = (float*)(wsb + 12800000);            //    320,000 B
  float* num             = (float*)(wsb + 13120000);            // 12,800,000 B
  unsigned short* swz    = (unsigned short*)(wsb + 25920000);   //    299,008 B
  int* cnt  = (int*)(wsb + 26220032);                           //     40,000 B
  int* rank = (int*)(wsb + 26260032);                           //     40,000 B (contiguous with cnt)
  int* perm = (int*)(wsb + 26300032);                           //    640,000 B -> ~26.9 MB

  // zero cnt+rank (adjacent: single 80KB memset) so the hist branch in
  // k_pre_all can run in the same launch without an init race
  hipMemsetAsync(cnt, 0, 80000, stream);
  k_pre_all<<<4000, 256, 0, stream>>>(node_input, Wsrc_s, Wsrc_v, bsrc, Wdst_s, Wdst_v,
                                      ms_s16, md_s16, ms_v16, md_v16,
                                      rad_W1, rad_W2, Wact_s, Wact_v, Wval_s, Wval_v,
                                      Walpha, w_int, swz, edst, cnt, num, den);
  k_scan_scatter<<<625, 256, 0, stream>>>(cnt, rank, edst, perm);
  e_all<<<10000, 256, 0, stream>>>(ms_s16, md_s16, ms_v16, md_v16, esrc, edst, perm, eattr, escal,
                                   rad_b1, rad_off, bact, bval,
                                   balpha, alpha_dot, swz, den, num);
  node_post<<<625, 256, 0, stream>>>(num, den, Wproj_s, bproj, Wproj_v, out);
}